// Round 11
// baseline (22704.753 us; speedup 1.0000x reference)
//
#include <hip/hip_runtime.h>
#include <hip/hip_bf16.h>

// Problem sizes (fixed by the reference)
#define SEQ   8192
#define DIN   1024
#define DH    2048
#define DOUT  1024

#define SENT 0x7fc0deadu  // quiet-NaN payload; tanh output can never equal this

// ---------------------------------------------------------------------------
// Fill hs with sentinel (must run every launch: harness does not re-poison ws)
// ---------------------------------------------------------------------------
__global__ __launch_bounds__(256) void fill_sent_kernel(uint4* __restrict__ p, size_t n4) {
    size_t i = (size_t)blockIdx.x * blockDim.x + threadIdx.x;
    size_t stride = (size_t)gridDim.x * blockDim.x;
    uint4 v = make_uint4(SENT, SENT, SENT, SENT);
    for (; i < n4; i += stride) p[i] = v;
}

// ---------------------------------------------------------------------------
// C[m][n] = bias[n] + sum_k A[m][k] * B[n][k]    (A: MxK, B: NxK, C: MxN)
// 64x64 tile, BK=16, 256 threads, 4x4 per-thread accumulators. fp32.
// ---------------------------------------------------------------------------
__global__ __launch_bounds__(256) void gemm_nt_bias(
    const float* __restrict__ A, const float* __restrict__ B,
    const float* __restrict__ bias, float* __restrict__ C,
    int M, int N, int K) {
    __shared__ float As[16][68];
    __shared__ float Bs[16][68];
    const int tid = threadIdx.x;
    const int bm = blockIdx.x * 64;
    const int bn = blockIdx.y * 64;
    const int lr = tid >> 2;
    const int lk = (tid & 3) * 4;
    const int tm = (tid >> 4) * 4;
    const int tn = (tid & 15) * 4;
    float acc[4][4] = {};

    for (int k0 = 0; k0 < K; k0 += 16) {
        const float4 av = *(const float4*)&A[(size_t)(bm + lr) * K + k0 + lk];
        const float4 bv = *(const float4*)&B[(size_t)(bn + lr) * K + k0 + lk];
        As[lk + 0][lr] = av.x; As[lk + 1][lr] = av.y;
        As[lk + 2][lr] = av.z; As[lk + 3][lr] = av.w;
        Bs[lk + 0][lr] = bv.x; Bs[lk + 1][lr] = bv.y;
        Bs[lk + 2][lr] = bv.z; Bs[lk + 3][lr] = bv.w;
        __syncthreads();
#pragma unroll
        for (int k = 0; k < 16; ++k) {
            const float4 a4 = *(const float4*)&As[k][tm];
            const float4 b4 = *(const float4*)&Bs[k][tn];
            const float a[4] = {a4.x, a4.y, a4.z, a4.w};
            const float b[4] = {b4.x, b4.y, b4.z, b4.w};
#pragma unroll
            for (int i = 0; i < 4; ++i)
#pragma unroll
                for (int j = 0; j < 4; ++j)
                    acc[i][j] = fmaf(a[i], b[j], acc[i][j]);
        }
        __syncthreads();
    }

    const float4 bv = *(const float4*)&bias[bn + tn];
#pragma unroll
    for (int i = 0; i < 4; ++i) {
        float4 o;
        o.x = acc[i][0] + bv.x;
        o.y = acc[i][1] + bv.y;
        o.z = acc[i][2] + bv.z;
        o.w = acc[i][3] + bv.w;
        *(float4*)&C[(size_t)(bm + tm + i) * N + bn + tn] = o;
    }
}

// ---------------------------------------------------------------------------
// Persistent recurrence: 128 WGs x 256 threads (R4/R9/R10 structure).
// ONLY change vs R10: PER-WAVE DIRECT PUBLISH. Each wave, the moment its
// reduce finishes, publishes its 4 rows straight from registers: lanes 0-3,
// one coalesced 16B PLAIN global_store_dword sc0 sc1 (write-through to MALL).
// Removes R10's h_out LDS stage + second barrier, decouples the 4 waves
// (3 of 4 publish earlier), and swaps the atomic-store path (possibly
// serialized sub-line application at MALL) for the plain store path.
// Detection stays safe: each consumer float4 (va/vb) maps 1:1 onto exactly
// one wave's 4-row-aligned 16B quarter-publish; all 8 words still checked.
// ---------------------------------------------------------------------------
__global__ __attribute__((amdgpu_flat_work_group_size(256, 256),
                          amdgpu_waves_per_eu(1, 1)))
void rnn_recurrence(
    const float* __restrict__ Whh, const float* __restrict__ xw,
    const float* __restrict__ h0, float* __restrict__ hs) {
    __shared__ float h_lds[2][DH];
    const int tid = threadIdx.x;
    const int wave = tid >> 6;
    const int lane = tid & 63;
    const int row0 = blockIdx.x * 16 + wave * 4;  // this wave's first row

    // Load this wave's 4x2048 weight slice and PIN it in registers.
    float4 w4[4][8];
#pragma unroll
    for (int r = 0; r < 4; ++r)
#pragma unroll
        for (int j = 0; j < 8; ++j) {
            w4[r][j] = *(const float4*)&Whh[(size_t)(row0 + r) * DH + lane * 4 + 256 * j];
            asm volatile("" : "+v"(w4[r][j].x), "+v"(w4[r][j].y),
                              "+v"(w4[r][j].z), "+v"(w4[r][j].w));
        }

    for (int t = 0; t < SEQ; ++t) {
        const int par = t & 1;
        // prefetch xw for this wave's rows (issues before the poll)
        const float xwv = xw[(size_t)t * DH + row0 + (lane & 3)];

        if (t == 0) {
#pragma unroll
            for (int j = 0; j < 8; ++j)
                h_lds[0][j * 256 + tid] = h0[j * 256 + tid];
        } else {
            // ---- asm-batched sentinel poll: 32B/thread, one RT per round ----
            const float* src = hs + (size_t)(t - 1) * DH;
            const float* a0 = src + 4 * tid;          // words [4t, 4t+4)
            const float* a1 = src + 1024 + 4 * tid;   // words [1024+4t, ..)
            float4 va, vb;
            unsigned bad;
            do {
                asm volatile(
                    "global_load_dwordx4 %0, %2, off sc0 sc1\n\t"
                    "global_load_dwordx4 %1, %3, off sc0 sc1\n\t"
                    "s_waitcnt vmcnt(0)"
                    : "=&v"(va), "=&v"(vb)
                    : "v"(a0), "v"(a1)
                    : "memory");
                bad = (__float_as_uint(va.x) == SENT) | (__float_as_uint(va.y) == SENT) |
                      (__float_as_uint(va.z) == SENT) | (__float_as_uint(va.w) == SENT) |
                      (__float_as_uint(vb.x) == SENT) | (__float_as_uint(vb.y) == SENT) |
                      (__float_as_uint(vb.z) == SENT) | (__float_as_uint(vb.w) == SENT);
            } while (__builtin_expect(bad != 0, 0));
            *(float4*)&h_lds[par][4 * tid] = va;
            *(float4*)&h_lds[par][1024 + 4 * tid] = vb;
        }
        __syncthreads();  // single barrier/step (double-buffered LDS)

        // ---- pull h into registers in the compute pattern ----
        float4 h4[8];
#pragma unroll
        for (int j = 0; j < 8; ++j)
            h4[j] = *(const float4*)&h_lds[par][lane * 4 + 256 * j];

        // ---- 4 rows x 32 cols of FMAs per lane ----
        float acc0 = 0.f, acc1 = 0.f, acc2 = 0.f, acc3 = 0.f;
#pragma unroll
        for (int j = 0; j < 8; ++j) {
            const float4 hv = h4[j];
            acc0 = fmaf(w4[0][j].x, hv.x, acc0); acc0 = fmaf(w4[0][j].y, hv.y, acc0);
            acc0 = fmaf(w4[0][j].z, hv.z, acc0); acc0 = fmaf(w4[0][j].w, hv.w, acc0);
            acc1 = fmaf(w4[1][j].x, hv.x, acc1); acc1 = fmaf(w4[1][j].y, hv.y, acc1);
            acc1 = fmaf(w4[1][j].z, hv.z, acc1); acc1 = fmaf(w4[1][j].w, hv.w, acc1);
            acc2 = fmaf(w4[2][j].x, hv.x, acc2); acc2 = fmaf(w4[2][j].y, hv.y, acc2);
            acc2 = fmaf(w4[2][j].z, hv.z, acc2); acc2 = fmaf(w4[2][j].w, hv.w, acc2);
            acc3 = fmaf(w4[3][j].x, hv.x, acc3); acc3 = fmaf(w4[3][j].y, hv.y, acc3);
            acc3 = fmaf(w4[3][j].w, hv.w, acc3); acc3 = fmaf(w4[3][j].z, hv.z, acc3);
        }

        // ---- select-merge butterfly: 7 shuffles, lane l ends with row (l&3) ----
        float a01 = (lane & 1) ? acc1 : acc0;
        float b01 = (lane & 1) ? acc0 : acc1;
        a01 += __shfl_xor(b01, 1);
        float a23 = (lane & 1) ? acc3 : acc2;
        float b23 = (lane & 1) ? acc2 : acc3;
        a23 += __shfl_xor(b23, 1);
        float a = (lane & 2) ? a23 : a01;
        float b = (lane & 2) ? a01 : a23;
        a += __shfl_xor(b, 2);
        a += __shfl_xor(a, 4);
        a += __shfl_xor(a, 8);
        a += __shfl_xor(a, 16);
        a += __shfl_xor(a, 32);

        // ---- tanh + immediate per-wave 16B coalesced plain publish ----
        if (lane < 4) {
            const float hval = tanhf(a + xwv);
            const float* dst = hs + (size_t)t * DH + row0 + lane;
            asm volatile("global_store_dword %0, %1, off sc0 sc1"
                         :: "v"(dst), "v"(hval) : "memory");
        }
    }
}

// ---------------------------------------------------------------------------
__global__ __launch_bounds__(256) void copy_hfinal(const float* __restrict__ hs,
                                                   float* __restrict__ out) {
    const int i = blockIdx.x * 256 + threadIdx.x;
    out[i] = hs[(size_t)(SEQ - 1) * DH + i];
}

// ---------------------------------------------------------------------------
extern "C" void kernel_launch(void* const* d_in, const int* in_sizes, int n_in,
                              void* d_out, int out_size, void* d_ws, size_t ws_size,
                              hipStream_t stream) {
    (void)in_sizes; (void)n_in; (void)out_size; (void)ws_size;
    const float* x_seq  = (const float*)d_in[0];  // (SEQ, DIN)
    const float* h0     = (const float*)d_in[1];  // (DH,)
    const float* W_ih   = (const float*)d_in[2];  // (DH, DIN)
    const float* W_hh   = (const float*)d_in[3];  // (DH, DH)
    const float* b_h    = (const float*)d_in[4];  // (DH,)
    const float* W_ho_w = (const float*)d_in[5];  // (DOUT, DH)
    const float* W_ho_b = (const float*)d_in[6];  // (DOUT,)
    float* out = (float*)d_out;                   // (SEQ*DOUT) then (DH,)

    float* xw = (float*)d_ws;                     // SEQ*DH fp32 = 64 MB
    float* hs = xw + (size_t)SEQ * DH;            // SEQ*DH fp32 = 64 MB

    // 1) sentinel-fill hs (dataflow flags)
    fill_sent_kernel<<<2048, 256, 0, stream>>>((uint4*)hs, (size_t)SEQ * DH / 4);

    // 2) xw = x_seq @ W_ih.T + b_h
    gemm_nt_bias<<<dim3(SEQ / 64, DH / 64), 256, 0, stream>>>(
        x_seq, W_ih, b_h, xw, SEQ, DH, DIN);

    // 3) sequential recurrence (persistent dataflow kernel)
    rnn_recurrence<<<DH / 16, 256, 0, stream>>>(W_hh, xw, h0, hs);

    // 4) out = hs @ W_ho_w.T + W_ho_b
    gemm_nt_bias<<<dim3(SEQ / 64, DOUT / 64), 256, 0, stream>>>(
        hs, W_ho_w, W_ho_b, out, SEQ, DOUT, DH);

    // 5) h_final
    copy_hfinal<<<DH / 256, 256, 0, stream>>>(hs, out + (size_t)SEQ * DOUT);
}

// Round 12
// 17789.763 us; speedup vs baseline: 1.2763x; 1.2763x over previous
//
#include <hip/hip_runtime.h>
#include <hip/hip_bf16.h>

// Problem sizes (fixed by the reference)
#define SEQ   8192
#define DIN   1024
#define DH    2048
#define DOUT  1024

#define SENT 0x7fc0deadu  // quiet-NaN payload; tanh output can never equal this

// ---------------------------------------------------------------------------
// Fill hs with sentinel (must run every launch: harness does not re-poison ws)
// ---------------------------------------------------------------------------
__global__ __launch_bounds__(256) void fill_sent_kernel(uint4* __restrict__ p, size_t n4) {
    size_t i = (size_t)blockIdx.x * blockDim.x + threadIdx.x;
    size_t stride = (size_t)gridDim.x * blockDim.x;
    uint4 v = make_uint4(SENT, SENT, SENT, SENT);
    for (; i < n4; i += stride) p[i] = v;
}

// ---------------------------------------------------------------------------
// C[m][n] = bias[n] + sum_k A[m][k] * B[n][k]    (A: MxK, B: NxK, C: MxN)
// 64x64 tile, BK=16, 256 threads, 4x4 per-thread accumulators. fp32.
// ---------------------------------------------------------------------------
__global__ __launch_bounds__(256) void gemm_nt_bias(
    const float* __restrict__ A, const float* __restrict__ B,
    const float* __restrict__ bias, float* __restrict__ C,
    int M, int N, int K) {
    __shared__ float As[16][68];
    __shared__ float Bs[16][68];
    const int tid = threadIdx.x;
    const int bm = blockIdx.x * 64;
    const int bn = blockIdx.y * 64;
    const int lr = tid >> 2;
    const int lk = (tid & 3) * 4;
    const int tm = (tid >> 4) * 4;
    const int tn = (tid & 15) * 4;
    float acc[4][4] = {};

    for (int k0 = 0; k0 < K; k0 += 16) {
        const float4 av = *(const float4*)&A[(size_t)(bm + lr) * K + k0 + lk];
        const float4 bv = *(const float4*)&B[(size_t)(bn + lr) * K + k0 + lk];
        As[lk + 0][lr] = av.x; As[lk + 1][lr] = av.y;
        As[lk + 2][lr] = av.z; As[lk + 3][lr] = av.w;
        Bs[lk + 0][lr] = bv.x; Bs[lk + 1][lr] = bv.y;
        Bs[lk + 2][lr] = bv.z; Bs[lk + 3][lr] = bv.w;
        __syncthreads();
#pragma unroll
        for (int k = 0; k < 16; ++k) {
            const float4 a4 = *(const float4*)&As[k][tm];
            const float4 b4 = *(const float4*)&Bs[k][tn];
            const float a[4] = {a4.x, a4.y, a4.z, a4.w};
            const float b[4] = {b4.x, b4.y, b4.z, b4.w};
#pragma unroll
            for (int i = 0; i < 4; ++i)
#pragma unroll
                for (int j = 0; j < 4; ++j)
                    acc[i][j] = fmaf(a[i], b[j], acc[i][j]);
        }
        __syncthreads();
    }

    const float4 bv = *(const float4*)&bias[bn + tn];
#pragma unroll
    for (int i = 0; i < 4; ++i) {
        float4 o;
        o.x = acc[i][0] + bv.x;
        o.y = acc[i][1] + bv.y;
        o.z = acc[i][2] + bv.z;
        o.w = acc[i][3] + bv.w;
        *(float4*)&C[(size_t)(bm + tm + i) * N + bn + tn] = o;
    }
}

// ---------------------------------------------------------------------------
// Persistent recurrence: 128 WGs x 256 threads. R10 structure (15.5ms proven):
// full-line publish via LDS gather + single 16-lane 64B store (R11 proved
// quarter-line publishes reintroduce 2x WRITE amplification + dribble).
// ONLY change vs R10: SELECTIVE RE-POLL. Round 1 reads both 1KB halves;
// re-rounds re-issue only halves still containing sentinels, gated
// wave-uniformly (__any, no divergence). Cuts re-round MALL request rate
// ~4x (theory: aggregate poll contention inflates RT; R6 showed 2x pollers
// -> 1.45x slower). Load+waitcnt fused per asm block (no hoist hazard).
// ---------------------------------------------------------------------------
__global__ __attribute__((amdgpu_flat_work_group_size(256, 256),
                          amdgpu_waves_per_eu(1, 1)))
void rnn_recurrence(
    const float* __restrict__ Whh, const float* __restrict__ xw,
    const float* __restrict__ h0, float* __restrict__ hs) {
    __shared__ float h_lds[2][DH];
    __shared__ float h_out[16];
    const int tid = threadIdx.x;
    const int wave = tid >> 6;
    const int lane = tid & 63;
    const int row0 = blockIdx.x * 16 + wave * 4;  // this wave's first row

    // Load this wave's 4x2048 weight slice and PIN it in registers.
    float4 w4[4][8];
#pragma unroll
    for (int r = 0; r < 4; ++r)
#pragma unroll
        for (int j = 0; j < 8; ++j) {
            w4[r][j] = *(const float4*)&Whh[(size_t)(row0 + r) * DH + lane * 4 + 256 * j];
            asm volatile("" : "+v"(w4[r][j].x), "+v"(w4[r][j].y),
                              "+v"(w4[r][j].z), "+v"(w4[r][j].w));
        }

    for (int t = 0; t < SEQ; ++t) {
        const int par = t & 1;
        // prefetch xw for this wave's rows (issues before the poll)
        const float xwv = xw[(size_t)t * DH + row0 + (lane & 3)];

        if (t == 0) {
#pragma unroll
            for (int j = 0; j < 8; ++j)
                h_lds[0][j * 256 + tid] = h0[j * 256 + tid];
        } else {
            // ---- selective asm-batched sentinel poll ----
            const float* src = hs + (size_t)(t - 1) * DH;
            const float* a0 = src + 4 * tid;          // words [4t, 4t+4)
            const float* a1 = src + 1024 + 4 * tid;   // words [1024+4t, ..)
            float4 va, vb;
            asm volatile(
                "global_load_dwordx4 %0, %2, off sc0 sc1\n\t"
                "global_load_dwordx4 %1, %3, off sc0 sc1\n\t"
                "s_waitcnt vmcnt(0)"
                : "=&v"(va), "=&v"(vb)
                : "v"(a0), "v"(a1)
                : "memory");
            for (;;) {
                const bool badA =
                    (__float_as_uint(va.x) == SENT) | (__float_as_uint(va.y) == SENT) |
                    (__float_as_uint(va.z) == SENT) | (__float_as_uint(va.w) == SENT);
                const bool badB =
                    (__float_as_uint(vb.x) == SENT) | (__float_as_uint(vb.y) == SENT) |
                    (__float_as_uint(vb.z) == SENT) | (__float_as_uint(vb.w) == SENT);
                const bool reA = __any((int)badA);  // wave-uniform
                const bool reB = __any((int)badB);
                if (__builtin_expect(!(reA | reB), 1)) break;
                if (reA & reB) {
                    asm volatile(
                        "global_load_dwordx4 %0, %2, off sc0 sc1\n\t"
                        "global_load_dwordx4 %1, %3, off sc0 sc1\n\t"
                        "s_waitcnt vmcnt(0)"
                        : "=&v"(va), "=&v"(vb) : "v"(a0), "v"(a1) : "memory");
                } else if (reA) {
                    asm volatile(
                        "global_load_dwordx4 %0, %1, off sc0 sc1\n\t"
                        "s_waitcnt vmcnt(0)"
                        : "=&v"(va) : "v"(a0) : "memory");
                } else {
                    asm volatile(
                        "global_load_dwordx4 %0, %1, off sc0 sc1\n\t"
                        "s_waitcnt vmcnt(0)"
                        : "=&v"(vb) : "v"(a1) : "memory");
                }
            }
            *(float4*)&h_lds[par][4 * tid] = va;
            *(float4*)&h_lds[par][1024 + 4 * tid] = vb;
        }
        __syncthreads();  // h[t-1] staged in LDS

        // ---- pull h into registers in the compute pattern ----
        float4 h4[8];
#pragma unroll
        for (int j = 0; j < 8; ++j)
            h4[j] = *(const float4*)&h_lds[par][lane * 4 + 256 * j];

        // ---- 4 rows x 32 cols of FMAs per lane ----
        float acc0 = 0.f, acc1 = 0.f, acc2 = 0.f, acc3 = 0.f;
#pragma unroll
        for (int j = 0; j < 8; ++j) {
            const float4 hv = h4[j];
            acc0 = fmaf(w4[0][j].x, hv.x, acc0); acc0 = fmaf(w4[0][j].y, hv.y, acc0);
            acc0 = fmaf(w4[0][j].z, hv.z, acc0); acc0 = fmaf(w4[0][j].w, hv.w, acc0);
            acc1 = fmaf(w4[1][j].x, hv.x, acc1); acc1 = fmaf(w4[1][j].y, hv.y, acc1);
            acc1 = fmaf(w4[1][j].z, hv.z, acc1); acc1 = fmaf(w4[1][j].w, hv.w, acc1);
            acc2 = fmaf(w4[2][j].x, hv.x, acc2); acc2 = fmaf(w4[2][j].y, hv.y, acc2);
            acc2 = fmaf(w4[2][j].z, hv.z, acc2); acc2 = fmaf(w4[2][j].w, hv.w, acc2);
            acc3 = fmaf(w4[3][j].x, hv.x, acc3); acc3 = fmaf(w4[3][j].y, hv.y, acc3);
            acc3 = fmaf(w4[3][j].z, hv.z, acc3); acc3 = fmaf(w4[3][j].w, hv.w, acc3);
        }

        // ---- select-merge butterfly: 7 shuffles, lane l ends with row (l&3) ----
        float a01 = (lane & 1) ? acc1 : acc0;
        float b01 = (lane & 1) ? acc0 : acc1;
        a01 += __shfl_xor(b01, 1);
        float a23 = (lane & 1) ? acc3 : acc2;
        float b23 = (lane & 1) ? acc2 : acc3;
        a23 += __shfl_xor(b23, 1);
        float a = (lane & 2) ? a23 : a01;
        float b = (lane & 2) ? a01 : a23;
        a += __shfl_xor(b, 2);
        a += __shfl_xor(a, 4);
        a += __shfl_xor(a, 8);
        a += __shfl_xor(a, 16);
        a += __shfl_xor(a, 32);

        // ---- tanh, stage into LDS, then ONE coalesced 64B line publish ----
        if (lane < 4)
            h_out[wave * 4 + lane] = tanhf(a + xwv);
        __syncthreads();  // all 16 values staged
        if (tid < 16)
            __hip_atomic_store((unsigned*)(hs + (size_t)t * DH + blockIdx.x * 16 + tid),
                               __float_as_uint(h_out[tid]),
                               __ATOMIC_RELAXED, __HIP_MEMORY_SCOPE_AGENT);
    }
}

// ---------------------------------------------------------------------------
__global__ __launch_bounds__(256) void copy_hfinal(const float* __restrict__ hs,
                                                   float* __restrict__ out) {
    const int i = blockIdx.x * 256 + threadIdx.x;
    out[i] = hs[(size_t)(SEQ - 1) * DH + i];
}

// ---------------------------------------------------------------------------
extern "C" void kernel_launch(void* const* d_in, const int* in_sizes, int n_in,
                              void* d_out, int out_size, void* d_ws, size_t ws_size,
                              hipStream_t stream) {
    (void)in_sizes; (void)n_in; (void)out_size; (void)ws_size;
    const float* x_seq  = (const float*)d_in[0];  // (SEQ, DIN)
    const float* h0     = (const float*)d_in[1];  // (DH,)
    const float* W_ih   = (const float*)d_in[2];  // (DH, DIN)
    const float* W_hh   = (const float*)d_in[3];  // (DH, DH)
    const float* b_h    = (const float*)d_in[4];  // (DH,)
    const float* W_ho_w = (const float*)d_in[5];  // (DOUT, DH)
    const float* W_ho_b = (const float*)d_in[6];  // (DOUT,)
    float* out = (float*)d_out;                   // (SEQ*DOUT) then (DH,)

    float* xw = (float*)d_ws;                     // SEQ*DH fp32 = 64 MB
    float* hs = xw + (size_t)SEQ * DH;            // SEQ*DH fp32 = 64 MB

    // 1) sentinel-fill hs (dataflow flags)
    fill_sent_kernel<<<2048, 256, 0, stream>>>((uint4*)hs, (size_t)SEQ * DH / 4);

    // 2) xw = x_seq @ W_ih.T + b_h
    gemm_nt_bias<<<dim3(SEQ / 64, DH / 64), 256, 0, stream>>>(
        x_seq, W_ih, b_h, xw, SEQ, DH, DIN);

    // 3) sequential recurrence (persistent dataflow kernel)
    rnn_recurrence<<<DH / 16, 256, 0, stream>>>(W_hh, xw, h0, hs);

    // 4) out = hs @ W_ho_w.T + W_ho_b
    gemm_nt_bias<<<dim3(SEQ / 64, DOUT / 64), 256, 0, stream>>>(
        hs, W_ho_w, W_ho_b, out, SEQ, DOUT, DH);

    // 5) h_final
    copy_hfinal<<<DH / 256, 256, 0, stream>>>(hs, out + (size_t)SEQ * DOUT);
}

// Round 13
// 15089.490 us; speedup vs baseline: 1.5047x; 1.1790x over previous
//
#include <hip/hip_runtime.h>
#include <hip/hip_bf16.h>

// Problem sizes (fixed by the reference)
#define SEQ   8192
#define DIN   1024
#define DH    2048
#define DOUT  1024

#define SENT 0x7fc0deadu  // quiet-NaN payload; tanh output can never equal this

// ---------------------------------------------------------------------------
// Fill hs with sentinel (must run every launch: harness does not re-poison ws)
// ---------------------------------------------------------------------------
__global__ __launch_bounds__(256) void fill_sent_kernel(uint4* __restrict__ p, size_t n4) {
    size_t i = (size_t)blockIdx.x * blockDim.x + threadIdx.x;
    size_t stride = (size_t)gridDim.x * blockDim.x;
    uint4 v = make_uint4(SENT, SENT, SENT, SENT);
    for (; i < n4; i += stride) p[i] = v;
}

// ---------------------------------------------------------------------------
// C[m][n] = bias[n] + sum_k A[m][k] * B[n][k]    (A: MxK, B: NxK, C: MxN)
// 64x64 tile, BK=16, 256 threads, 4x4 per-thread accumulators. fp32.
// ---------------------------------------------------------------------------
__global__ __launch_bounds__(256) void gemm_nt_bias(
    const float* __restrict__ A, const float* __restrict__ B,
    const float* __restrict__ bias, float* __restrict__ C,
    int M, int N, int K) {
    __shared__ float As[16][68];
    __shared__ float Bs[16][68];
    const int tid = threadIdx.x;
    const int bm = blockIdx.x * 64;
    const int bn = blockIdx.y * 64;
    const int lr = tid >> 2;
    const int lk = (tid & 3) * 4;
    const int tm = (tid >> 4) * 4;
    const int tn = (tid & 15) * 4;
    float acc[4][4] = {};

    for (int k0 = 0; k0 < K; k0 += 16) {
        const float4 av = *(const float4*)&A[(size_t)(bm + lr) * K + k0 + lk];
        const float4 bv = *(const float4*)&B[(size_t)(bn + lr) * K + k0 + lk];
        As[lk + 0][lr] = av.x; As[lk + 1][lr] = av.y;
        As[lk + 2][lr] = av.z; As[lk + 3][lr] = av.w;
        Bs[lk + 0][lr] = bv.x; Bs[lk + 1][lr] = bv.y;
        Bs[lk + 2][lr] = bv.z; Bs[lk + 3][lr] = bv.w;
        __syncthreads();
#pragma unroll
        for (int k = 0; k < 16; ++k) {
            const float4 a4 = *(const float4*)&As[k][tm];
            const float4 b4 = *(const float4*)&Bs[k][tn];
            const float a[4] = {a4.x, a4.y, a4.z, a4.w};
            const float b[4] = {b4.x, b4.y, b4.z, b4.w};
#pragma unroll
            for (int i = 0; i < 4; ++i)
#pragma unroll
                for (int j = 0; j < 4; ++j)
                    acc[i][j] = fmaf(a[i], b[j], acc[i][j]);
        }
        __syncthreads();
    }

    const float4 bv = *(const float4*)&bias[bn + tn];
#pragma unroll
    for (int i = 0; i < 4; ++i) {
        float4 o;
        o.x = acc[i][0] + bv.x;
        o.y = acc[i][1] + bv.y;
        o.z = acc[i][2] + bv.z;
        o.w = acc[i][3] + bv.w;
        *(float4*)&C[(size_t)(bm + tm + i) * N + bn + tn] = o;
    }
}

// ---------------------------------------------------------------------------
// Persistent recurrence: 128 WGs x 512 THREADS (8 waves), one WG per CU.
// R13 change vs R10: 2 rows/wave instead of 4 -> 64 weight floats/lane.
// R10's VGPR_Count=132 < the 128 pinned weight floats alone => compiler was
// SPILLING ~60-80 weight floats to scratch and re-streaming them through
// L1/L2 every step (the mystery ~590MB of FETCH_SIZE). 64+32+misc ~= 116
// regs fits what the compiler demonstrably allocates -> spill impossible.
// Everything else is R10 verbatim: asm-batched data-is-flag poll (now ONE
// dwordx4/thread), LDS h staging, select-merge butterfly (6 shuffles),
// LDS-gathered single 16-lane 64B full-line publish (R11 proved quarter-line
// publishes cost 6ms). Per-row summation tree is bit-identical to R10.
// ---------------------------------------------------------------------------
__global__ __attribute__((amdgpu_flat_work_group_size(512, 512),
                          amdgpu_waves_per_eu(2, 2)))
void rnn_recurrence(
    const float* __restrict__ Whh, const float* __restrict__ xw,
    const float* __restrict__ h0, float* __restrict__ hs) {
    __shared__ float h_lds[2][DH];
    __shared__ float h_out[16];
    const int tid = threadIdx.x;
    const int wave = tid >> 6;
    const int lane = tid & 63;
    const int row0 = blockIdx.x * 16 + wave * 2;  // this wave's first row

    // Load this wave's 2x2048 weight slice and PIN it in registers (64 fl).
    float4 w4[2][8];
#pragma unroll
    for (int r = 0; r < 2; ++r)
#pragma unroll
        for (int j = 0; j < 8; ++j) {
            w4[r][j] = *(const float4*)&Whh[(size_t)(row0 + r) * DH + lane * 4 + 256 * j];
            asm volatile("" : "+v"(w4[r][j].x), "+v"(w4[r][j].y),
                              "+v"(w4[r][j].z), "+v"(w4[r][j].w));
        }

    for (int t = 0; t < SEQ; ++t) {
        const int par = t & 1;
        // prefetch xw for this wave's rows (issues before the poll)
        const float xwv = xw[(size_t)t * DH + row0 + (lane & 1)];

        if (t == 0) {
            *(float4*)&h_lds[0][4 * tid] = *(const float4*)&h0[4 * tid];
        } else {
            // ---- asm-batched sentinel poll: 16B/thread, one RT per round ----
            const float* src = hs + (size_t)(t - 1) * DH;
            const float* a0 = src + 4 * tid;          // words [4t, 4t+4)
            float4 va;
            unsigned bad;
            do {
                asm volatile(
                    "global_load_dwordx4 %0, %1, off sc0 sc1\n\t"
                    "s_waitcnt vmcnt(0)"
                    : "=&v"(va)
                    : "v"(a0)
                    : "memory");
                bad = (__float_as_uint(va.x) == SENT) | (__float_as_uint(va.y) == SENT) |
                      (__float_as_uint(va.z) == SENT) | (__float_as_uint(va.w) == SENT);
            } while (__builtin_expect(bad != 0, 0));
            *(float4*)&h_lds[par][4 * tid] = va;
        }
        __syncthreads();  // h[t-1] staged in LDS

        // ---- pull h into registers in the compute pattern ----
        float4 h4[8];
#pragma unroll
        for (int j = 0; j < 8; ++j)
            h4[j] = *(const float4*)&h_lds[par][lane * 4 + 256 * j];

        // ---- 2 rows x 32 cols of FMAs per lane ----
        float acc0 = 0.f, acc1 = 0.f;
#pragma unroll
        for (int j = 0; j < 8; ++j) {
            const float4 hv = h4[j];
            acc0 = fmaf(w4[0][j].x, hv.x, acc0); acc0 = fmaf(w4[0][j].y, hv.y, acc0);
            acc0 = fmaf(w4[0][j].z, hv.z, acc0); acc0 = fmaf(w4[0][j].w, hv.w, acc0);
            acc1 = fmaf(w4[1][j].x, hv.x, acc1); acc1 = fmaf(w4[1][j].y, hv.y, acc1);
            acc1 = fmaf(w4[1][j].z, hv.z, acc1); acc1 = fmaf(w4[1][j].w, hv.w, acc1);
        }

        // ---- select-merge butterfly: 6 shuffles, lane l ends with row (l&1) ----
        float p = (lane & 1) ? acc1 : acc0;
        float q = (lane & 1) ? acc0 : acc1;
        p += __shfl_xor(q, 1);
        p += __shfl_xor(p, 2);
        p += __shfl_xor(p, 4);
        p += __shfl_xor(p, 8);
        p += __shfl_xor(p, 16);
        p += __shfl_xor(p, 32);

        // ---- tanh, stage into LDS, then ONE coalesced 64B line publish ----
        if (lane < 2)
            h_out[wave * 2 + lane] = tanhf(p + xwv);
        __syncthreads();  // all 16 values staged
        if (tid < 16)
            __hip_atomic_store((unsigned*)(hs + (size_t)t * DH + blockIdx.x * 16 + tid),
                               __float_as_uint(h_out[tid]),
                               __ATOMIC_RELAXED, __HIP_MEMORY_SCOPE_AGENT);
    }
}

// ---------------------------------------------------------------------------
__global__ __launch_bounds__(256) void copy_hfinal(const float* __restrict__ hs,
                                                   float* __restrict__ out) {
    const int i = blockIdx.x * 256 + threadIdx.x;
    out[i] = hs[(size_t)(SEQ - 1) * DH + i];
}

// ---------------------------------------------------------------------------
extern "C" void kernel_launch(void* const* d_in, const int* in_sizes, int n_in,
                              void* d_out, int out_size, void* d_ws, size_t ws_size,
                              hipStream_t stream) {
    (void)in_sizes; (void)n_in; (void)out_size; (void)ws_size;
    const float* x_seq  = (const float*)d_in[0];  // (SEQ, DIN)
    const float* h0     = (const float*)d_in[1];  // (DH,)
    const float* W_ih   = (const float*)d_in[2];  // (DH, DIN)
    const float* W_hh   = (const float*)d_in[3];  // (DH, DH)
    const float* b_h    = (const float*)d_in[4];  // (DH,)
    const float* W_ho_w = (const float*)d_in[5];  // (DOUT, DH)
    const float* W_ho_b = (const float*)d_in[6];  // (DOUT,)
    float* out = (float*)d_out;                   // (SEQ*DOUT) then (DH,)

    float* xw = (float*)d_ws;                     // SEQ*DH fp32 = 64 MB
    float* hs = xw + (size_t)SEQ * DH;            // SEQ*DH fp32 = 64 MB

    // 1) sentinel-fill hs (dataflow flags)
    fill_sent_kernel<<<2048, 256, 0, stream>>>((uint4*)hs, (size_t)SEQ * DH / 4);

    // 2) xw = x_seq @ W_ih.T + b_h
    gemm_nt_bias<<<dim3(SEQ / 64, DH / 64), 256, 0, stream>>>(
        x_seq, W_ih, b_h, xw, SEQ, DH, DIN);

    // 3) sequential recurrence (persistent dataflow kernel)
    rnn_recurrence<<<DH / 16, 512, 0, stream>>>(W_hh, xw, h0, hs);

    // 4) out = hs @ W_ho_w.T + W_ho_b
    gemm_nt_bias<<<dim3(SEQ / 64, DOUT / 64), 256, 0, stream>>>(
        hs, W_ho_w, W_ho_b, out, SEQ, DOUT, DH);

    // 5) h_final
    copy_hfinal<<<DH / 256, 256, 0, stream>>>(hs, out + (size_t)SEQ * DOUT);
}

// Round 17
// 14999.098 us; speedup vs baseline: 1.5137x; 1.0060x over previous
//
#include <hip/hip_runtime.h>
#include <hip/hip_bf16.h>

// Problem sizes (fixed by the reference)
#define SEQ   8192
#define DIN   1024
#define DH    2048
#define DOUT  1024

#define SENT 0x7fc0deadu  // quiet-NaN payload; tanh output can never equal this

// ---------------------------------------------------------------------------
// Fill hs with sentinel (must run every launch: harness does not re-poison ws)
// ---------------------------------------------------------------------------
__global__ __launch_bounds__(256) void fill_sent_kernel(uint4* __restrict__ p, size_t n4) {
    size_t i = (size_t)blockIdx.x * blockDim.x + threadIdx.x;
    size_t stride = (size_t)gridDim.x * blockDim.x;
    uint4 v = make_uint4(SENT, SENT, SENT, SENT);
    for (; i < n4; i += stride) p[i] = v;
}

// ---------------------------------------------------------------------------
// C[m][n] = bias[n] + sum_k A[m][k] * B[n][k]    (A: MxK, B: NxK, C: MxN)
// 128x64 tile, BK=16, 256 threads, 8x4 per-thread accumulators. fp32.
// (R17: retiled from 64x64/4x4 -- 2x arithmetic intensity; recurrence is
//  93% of runtime but this is the only safe lever left.)
// ---------------------------------------------------------------------------
__global__ __launch_bounds__(256) void gemm_nt_bias(
    const float* __restrict__ A, const float* __restrict__ B,
    const float* __restrict__ bias, float* __restrict__ C,
    int M, int N, int K) {
    __shared__ float As[16][132];   // [k][m-row], +4 pad
    __shared__ float Bs[16][68];    // [k][n-row], +4 pad
    const int tid = threadIdx.x;
    const int bm = blockIdx.x * 128;
    const int bn = blockIdx.y * 64;
    // A staging: row = tid>>1 (0..127), k-half = (tid&1)*8  (8 floats each)
    const int alr = tid >> 1;
    const int alk = (tid & 1) * 8;
    // B staging: row = tid>>2 (0..63), k-quad = (tid&3)*4   (4 floats each)
    const int blr = tid >> 2;
    const int blk = (tid & 3) * 4;
    // micro-tile: tm in {0,8,..,120}, tn in {0,4,..,60}
    const int tm = (tid >> 4) * 8;
    const int tn = (tid & 15) * 4;
    float acc[8][4] = {};

    for (int k0 = 0; k0 < K; k0 += 16) {
        const float4 a0 = *(const float4*)&A[(size_t)(bm + alr) * K + k0 + alk];
        const float4 a1 = *(const float4*)&A[(size_t)(bm + alr) * K + k0 + alk + 4];
        const float4 bv = *(const float4*)&B[(size_t)(bn + blr) * K + k0 + blk];
        As[alk + 0][alr] = a0.x; As[alk + 1][alr] = a0.y;
        As[alk + 2][alr] = a0.z; As[alk + 3][alr] = a0.w;
        As[alk + 4][alr] = a1.x; As[alk + 5][alr] = a1.y;
        As[alk + 6][alr] = a1.z; As[alk + 7][alr] = a1.w;
        Bs[blk + 0][blr] = bv.x; Bs[blk + 1][blr] = bv.y;
        Bs[blk + 2][blr] = bv.z; Bs[blk + 3][blr] = bv.w;
        __syncthreads();
#pragma unroll
        for (int k = 0; k < 16; ++k) {
            const float4 af0 = *(const float4*)&As[k][tm];
            const float4 af1 = *(const float4*)&As[k][tm + 4];
            const float4 bf  = *(const float4*)&Bs[k][tn];
            const float a[8] = {af0.x, af0.y, af0.z, af0.w,
                                af1.x, af1.y, af1.z, af1.w};
            const float b[4] = {bf.x, bf.y, bf.z, bf.w};
#pragma unroll
            for (int i = 0; i < 8; ++i)
#pragma unroll
                for (int j = 0; j < 4; ++j)
                    acc[i][j] = fmaf(a[i], b[j], acc[i][j]);
        }
        __syncthreads();
    }

    const float4 bv = *(const float4*)&bias[bn + tn];
#pragma unroll
    for (int i = 0; i < 8; ++i) {
        float4 o;
        o.x = acc[i][0] + bv.x;
        o.y = acc[i][1] + bv.y;
        o.z = acc[i][2] + bv.z;
        o.w = acc[i][3] + bv.w;
        *(float4*)&C[(size_t)(bm + tm + i) * N + bn + tn] = o;
    }
}

// ---------------------------------------------------------------------------
// Persistent recurrence: 128 WGs x 512 threads -- R13 VERBATIM (14.1ms,
// passed, absmax 0.015625). After R14-R16's three silent-corruption failures,
// the ping-pong/raw-barrier detect class is retired: any overlap of poll
// loads across barriers needs exactly the dangling-load pattern that keeps
// corrupting, and __syncthreads' implicit vmcnt(0) drain makes the safe
// variant gainless. Structure: 2 rows/wave (64 pinned weight floats/lane,
// VGPR=88, no spill), single dwordx4 sc0sc1 data-is-flag poll per thread,
// LDS h staging (double-buffered), 6-shuffle select-merge reduce, LDS-
// gathered single 16-lane 64B FULL-LINE publish (R10/R11: quarter-lines
// cost 2x WRITE amplification + 6ms).
// ---------------------------------------------------------------------------
__global__ __attribute__((amdgpu_flat_work_group_size(512, 512),
                          amdgpu_waves_per_eu(2, 2)))
void rnn_recurrence(
    const float* __restrict__ Whh, const float* __restrict__ xw,
    const float* __restrict__ h0, float* __restrict__ hs) {
    __shared__ float h_lds[2][DH];
    __shared__ float h_out[16];
    const int tid = threadIdx.x;
    const int wave = tid >> 6;
    const int lane = tid & 63;
    const int row0 = blockIdx.x * 16 + wave * 2;  // this wave's first row

    // Load this wave's 2x2048 weight slice and PIN it in registers (64 fl).
    float4 w4[2][8];
#pragma unroll
    for (int r = 0; r < 2; ++r)
#pragma unroll
        for (int j = 0; j < 8; ++j) {
            w4[r][j] = *(const float4*)&Whh[(size_t)(row0 + r) * DH + lane * 4 + 256 * j];
            asm volatile("" : "+v"(w4[r][j].x), "+v"(w4[r][j].y),
                              "+v"(w4[r][j].z), "+v"(w4[r][j].w));
        }

    for (int t = 0; t < SEQ; ++t) {
        const int par = t & 1;
        // prefetch xw for this wave's rows (issues before the poll)
        const float xwv = xw[(size_t)t * DH + row0 + (lane & 1)];

        if (t == 0) {
            *(float4*)&h_lds[0][4 * tid] = *(const float4*)&h0[4 * tid];
        } else {
            // ---- asm-batched sentinel poll: 16B/thread, one RT per round ----
            const float* src = hs + (size_t)(t - 1) * DH;
            const float* a0 = src + 4 * tid;          // words [4t, 4t+4)
            float4 va;
            unsigned bad;
            do {
                asm volatile(
                    "global_load_dwordx4 %0, %1, off sc0 sc1\n\t"
                    "s_waitcnt vmcnt(0)"
                    : "=&v"(va)
                    : "v"(a0)
                    : "memory");
                bad = (__float_as_uint(va.x) == SENT) | (__float_as_uint(va.y) == SENT) |
                      (__float_as_uint(va.z) == SENT) | (__float_as_uint(va.w) == SENT);
            } while (__builtin_expect(bad != 0, 0));
            *(float4*)&h_lds[par][4 * tid] = va;
        }
        __syncthreads();  // h[t-1] staged in LDS

        // ---- pull h into registers in the compute pattern ----
        float4 h4[8];
#pragma unroll
        for (int j = 0; j < 8; ++j)
            h4[j] = *(const float4*)&h_lds[par][lane * 4 + 256 * j];

        // ---- 2 rows x 32 cols of FMAs per lane ----
        float acc0 = 0.f, acc1 = 0.f;
#pragma unroll
        for (int j = 0; j < 8; ++j) {
            const float4 hv = h4[j];
            acc0 = fmaf(w4[0][j].x, hv.x, acc0); acc0 = fmaf(w4[0][j].y, hv.y, acc0);
            acc0 = fmaf(w4[0][j].z, hv.z, acc0); acc0 = fmaf(w4[0][j].w, hv.w, acc0);
            acc1 = fmaf(w4[1][j].x, hv.x, acc1); acc1 = fmaf(w4[1][j].y, hv.y, acc1);
            acc1 = fmaf(w4[1][j].z, hv.z, acc1); acc1 = fmaf(w4[1][j].w, hv.w, acc1);
        }

        // ---- select-merge butterfly: 6 shuffles, lane l ends with row (l&1) ----
        float p = (lane & 1) ? acc1 : acc0;
        float q = (lane & 1) ? acc0 : acc1;
        p += __shfl_xor(q, 1);
        p += __shfl_xor(p, 2);
        p += __shfl_xor(p, 4);
        p += __shfl_xor(p, 8);
        p += __shfl_xor(p, 16);
        p += __shfl_xor(p, 32);

        // ---- tanh, stage into LDS, then ONE coalesced 64B line publish ----
        if (lane < 2)
            h_out[wave * 2 + lane] = tanhf(p + xwv);
        __syncthreads();  // all 16 values staged
        if (tid < 16)
            __hip_atomic_store((unsigned*)(hs + (size_t)t * DH + blockIdx.x * 16 + tid),
                               __float_as_uint(h_out[tid]),
                               __ATOMIC_RELAXED, __HIP_MEMORY_SCOPE_AGENT);
    }
}

// ---------------------------------------------------------------------------
__global__ __launch_bounds__(256) void copy_hfinal(const float* __restrict__ hs,
                                                   float* __restrict__ out) {
    const int i = blockIdx.x * 256 + threadIdx.x;
    out[i] = hs[(size_t)(SEQ - 1) * DH + i];
}

// ---------------------------------------------------------------------------
extern "C" void kernel_launch(void* const* d_in, const int* in_sizes, int n_in,
                              void* d_out, int out_size, void* d_ws, size_t ws_size,
                              hipStream_t stream) {
    (void)in_sizes; (void)n_in; (void)out_size; (void)ws_size;
    const float* x_seq  = (const float*)d_in[0];  // (SEQ, DIN)
    const float* h0     = (const float*)d_in[1];  // (DH,)
    const float* W_ih   = (const float*)d_in[2];  // (DH, DIN)
    const float* W_hh   = (const float*)d_in[3];  // (DH, DH)
    const float* b_h    = (const float*)d_in[4];  // (DH,)
    const float* W_ho_w = (const float*)d_in[5];  // (DOUT, DH)
    const float* W_ho_b = (const float*)d_in[6];  // (DOUT,)
    float* out = (float*)d_out;                   // (SEQ*DOUT) then (DH,)

    float* xw = (float*)d_ws;                     // SEQ*DH fp32 = 64 MB
    float* hs = xw + (size_t)SEQ * DH;            // SEQ*DH fp32 = 64 MB

    // 1) sentinel-fill hs (dataflow flags)
    fill_sent_kernel<<<2048, 256, 0, stream>>>((uint4*)hs, (size_t)SEQ * DH / 4);

    // 2) xw = x_seq @ W_ih.T + b_h    (128x64 tiles)
    gemm_nt_bias<<<dim3(SEQ / 128, DH / 64), 256, 0, stream>>>(
        x_seq, W_ih, b_h, xw, SEQ, DH, DIN);

    // 3) sequential recurrence (persistent dataflow kernel, R13 structure)
    rnn_recurrence<<<DH / 16, 512, 0, stream>>>(W_hh, xw, h0, hs);

    // 4) out = hs @ W_ho_w.T + W_ho_b  (128x64 tiles)
    gemm_nt_bias<<<dim3(SEQ / 128, DOUT / 64), 256, 0, stream>>>(
        hs, W_ho_w, W_ho_b, out, SEQ, DOUT, DH);

    // 5) h_final
    copy_hfinal<<<DH / 256, 256, 0, stream>>>(hs, out + (size_t)SEQ * DOUT);
}

// Round 18
// 14570.320 us; speedup vs baseline: 1.5583x; 1.0294x over previous
//
#include <hip/hip_runtime.h>
#include <hip/hip_bf16.h>

// Problem sizes (fixed by the reference)
#define SEQ   8192
#define DIN   1024
#define DH    2048
#define DOUT  1024

#define SENT 0x7fc0deadu  // quiet-NaN payload; tanh output can never equal this

// ---------------------------------------------------------------------------
// Fill hs with sentinel (must run every launch: harness does not re-poison ws)
// ---------------------------------------------------------------------------
__global__ __launch_bounds__(256) void fill_sent_kernel(uint4* __restrict__ p, size_t n4) {
    size_t i = (size_t)blockIdx.x * blockDim.x + threadIdx.x;
    size_t stride = (size_t)gridDim.x * blockDim.x;
    uint4 v = make_uint4(SENT, SENT, SENT, SENT);
    for (; i < n4; i += stride) p[i] = v;
}

// ---------------------------------------------------------------------------
// C[m][n] = bias[n] + sum_k A[m][k] * B[n][k]    (A: MxK, B: NxK, C: MxN)
// 128x64 tile, BK=16, 256 threads, 8x4 per-thread accumulators. fp32. (R17)
// ---------------------------------------------------------------------------
__global__ __launch_bounds__(256) void gemm_nt_bias(
    const float* __restrict__ A, const float* __restrict__ B,
    const float* __restrict__ bias, float* __restrict__ C,
    int M, int N, int K) {
    __shared__ float As[16][132];
    __shared__ float Bs[16][68];
    const int tid = threadIdx.x;
    const int bm = blockIdx.x * 128;
    const int bn = blockIdx.y * 64;
    const int alr = tid >> 1;
    const int alk = (tid & 1) * 8;
    const int blr = tid >> 2;
    const int blk = (tid & 3) * 4;
    const int tm = (tid >> 4) * 8;
    const int tn = (tid & 15) * 4;
    float acc[8][4] = {};

    for (int k0 = 0; k0 < K; k0 += 16) {
        const float4 a0 = *(const float4*)&A[(size_t)(bm + alr) * K + k0 + alk];
        const float4 a1 = *(const float4*)&A[(size_t)(bm + alr) * K + k0 + alk + 4];
        const float4 bv = *(const float4*)&B[(size_t)(bn + blr) * K + k0 + blk];
        As[alk + 0][alr] = a0.x; As[alk + 1][alr] = a0.y;
        As[alk + 2][alr] = a0.z; As[alk + 3][alr] = a0.w;
        As[alk + 4][alr] = a1.x; As[alk + 5][alr] = a1.y;
        As[alk + 6][alr] = a1.z; As[alk + 7][alr] = a1.w;
        Bs[blk + 0][blr] = bv.x; Bs[blk + 1][blr] = bv.y;
        Bs[blk + 2][blr] = bv.z; Bs[blk + 3][blr] = bv.w;
        __syncthreads();
#pragma unroll
        for (int k = 0; k < 16; ++k) {
            const float4 af0 = *(const float4*)&As[k][tm];
            const float4 af1 = *(const float4*)&As[k][tm + 4];
            const float4 bf  = *(const float4*)&Bs[k][tn];
            const float a[8] = {af0.x, af0.y, af0.z, af0.w,
                                af1.x, af1.y, af1.z, af1.w};
            const float b[4] = {bf.x, bf.y, bf.z, bf.w};
#pragma unroll
            for (int i = 0; i < 8; ++i)
#pragma unroll
                for (int j = 0; j < 4; ++j)
                    acc[i][j] = fmaf(a[i], b[j], acc[i][j]);
        }
        __syncthreads();
    }

    const float4 bv = *(const float4*)&bias[bn + tn];
#pragma unroll
    for (int i = 0; i < 8; ++i) {
        float4 o;
        o.x = acc[i][0] + bv.x;
        o.y = acc[i][1] + bv.y;
        o.z = acc[i][2] + bv.z;
        o.w = acc[i][3] + bv.w;
        *(float4*)&C[(size_t)(bm + tm + i) * N + bn + tn] = o;
    }
}

// ---------------------------------------------------------------------------
// Persistent recurrence R18: 128 WGs x 512 threads, COLUMN-PARTITIONED,
// ONE barrier per step.
//   thread tid owns h columns [4*tid, 4*tid+4) == exactly the 16B it polls.
//   poll (R13-verbatim single dwordx4 sc0sc1 data-is-flag) -> registers ->
//   IMMEDIATE 16-row x 4-col partial FMAs (no LDS stage, no first barrier;
//   poll-to-use is same-thread).
//   4-stage select-merge across the wave (keep rows whose bit k == lane bit
//   k; lane ends holding row lane&15) + xor16/xor32 adds -> per-wave row
//   partial. lanes 0-15 write part[par][wave][row]; ONE __syncthreads;
//   tid<16 sums 8 wave-partials + xw, tanh, and publishes the R10-proven
//   single 16-lane 64B FULL-LINE store. part[][] double-buffered by step
//   parity (next step's writes hit the other buffer -> no read/write race).
// Detect-pipelining class retired for good: k-deep ping-pong pays (k-1)/k*RT
// drain at exit vs RT/4 sampling gain -> net negative even when correct
// (and 0/3 correct: R14-R16).
// ---------------------------------------------------------------------------
__global__ __attribute__((amdgpu_flat_work_group_size(512, 512),
                          amdgpu_waves_per_eu(2, 2)))
void rnn_recurrence(
    const float* __restrict__ Whh, const float* __restrict__ xw,
    const float* __restrict__ h0, float* __restrict__ hs) {
    __shared__ float part[2][8][16];
    const int tid = threadIdx.x;
    const int wave = tid >> 6;
    const int lane = tid & 63;
    const int rbase = blockIdx.x * 16;   // this WG's 16 output rows
    const int c0 = 4 * tid;              // this thread's 4 h-columns

    // Weights: W[rbase+r][c0..c0+4) for r=0..15 (64 floats/lane), pinned.
    float4 w[16];
#pragma unroll
    for (int r = 0; r < 16; ++r) {
        w[r] = *(const float4*)&Whh[(size_t)(rbase + r) * DH + c0];
        asm volatile("" : "+v"(w[r].x), "+v"(w[r].y), "+v"(w[r].z), "+v"(w[r].w));
    }

    for (int t = 0; t < SEQ; ++t) {
        const int par = t & 1;
        // publisher threads prefetch their xw value (independent load)
        float xwv = 0.f;
        if (tid < 16) xwv = xw[(size_t)t * DH + rbase + tid];

        // ---- h[t-1] columns for this thread, straight into registers ----
        float4 hv;
        if (t == 0) {
            hv = *(const float4*)&h0[c0];
        } else {
            const float* a0 = hs + (size_t)(t - 1) * DH + c0;
            unsigned bad;
            do {
                asm volatile(
                    "global_load_dwordx4 %0, %1, off sc0 sc1\n\t"
                    "s_waitcnt vmcnt(0)"
                    : "=&v"(hv) : "v"(a0) : "memory");
                bad = (__float_as_uint(hv.x) == SENT) | (__float_as_uint(hv.y) == SENT) |
                      (__float_as_uint(hv.z) == SENT) | (__float_as_uint(hv.w) == SENT);
            } while (__builtin_expect(bad != 0, 0));
        }

        // ---- 16 rows x 4 cols partial dot products (starts immediately) ----
        float acc[16];
#pragma unroll
        for (int r = 0; r < 16; ++r)
            acc[r] = fmaf(w[r].w, hv.w,
                     fmaf(w[r].z, hv.z,
                     fmaf(w[r].y, hv.y, w[r].x * hv.x)));

        // ---- select-merge: 16 accs -> lane holds full-wave partial of row
        //      (lane&15). Stage k keeps rows whose bit k equals lane bit k.
        const bool b0 = (lane & 1) != 0, b1 = (lane & 2) != 0,
                   b2 = (lane & 4) != 0, b3 = (lane & 8) != 0;
        float s8[8];
#pragma unroll
        for (int j = 0; j < 8; ++j) {
            const float k = b0 ? acc[2 * j + 1] : acc[2 * j];
            const float g = b0 ? acc[2 * j]     : acc[2 * j + 1];
            s8[j] = k + __shfl_xor(g, 1);
        }
        float s4[4];
#pragma unroll
        for (int j = 0; j < 4; ++j) {
            const float k = b1 ? s8[2 * j + 1] : s8[2 * j];
            const float g = b1 ? s8[2 * j]     : s8[2 * j + 1];
            s4[j] = k + __shfl_xor(g, 2);
        }
        float s2[2];
#pragma unroll
        for (int j = 0; j < 2; ++j) {
            const float k = b2 ? s4[2 * j + 1] : s4[2 * j];
            const float g = b2 ? s4[2 * j]     : s4[2 * j + 1];
            s2[j] = k + __shfl_xor(g, 4);
        }
        float s1;
        {
            const float k = b3 ? s2[1] : s2[0];
            const float g = b3 ? s2[0] : s2[1];
            s1 = k + __shfl_xor(g, 8);
        }
        s1 += __shfl_xor(s1, 16);
        s1 += __shfl_xor(s1, 32);

        // ---- per-wave partials -> LDS (parity-buffered), ONE barrier ----
        if (lane < 16) part[par][wave][lane] = s1;
        __syncthreads();

        // ---- tid<16: finalize row tid and publish the full 64B line ----
        if (tid < 16) {
            const float sum =
                part[par][0][tid] + part[par][1][tid] + part[par][2][tid] +
                part[par][3][tid] + part[par][4][tid] + part[par][5][tid] +
                part[par][6][tid] + part[par][7][tid];
            const float hval = tanhf(sum + xwv);
            __hip_atomic_store((unsigned*)(hs + (size_t)t * DH + rbase + tid),
                               __float_as_uint(hval),
                               __ATOMIC_RELAXED, __HIP_MEMORY_SCOPE_AGENT);
        }
    }
}

// ---------------------------------------------------------------------------
__global__ __launch_bounds__(256) void copy_hfinal(const float* __restrict__ hs,
                                                   float* __restrict__ out) {
    const int i = blockIdx.x * 256 + threadIdx.x;
    out[i] = hs[(size_t)(SEQ - 1) * DH + i];
}

// ---------------------------------------------------------------------------
extern "C" void kernel_launch(void* const* d_in, const int* in_sizes, int n_in,
                              void* d_out, int out_size, void* d_ws, size_t ws_size,
                              hipStream_t stream) {
    (void)in_sizes; (void)n_in; (void)out_size; (void)ws_size;
    const float* x_seq  = (const float*)d_in[0];  // (SEQ, DIN)
    const float* h0     = (const float*)d_in[1];  // (DH,)
    const float* W_ih   = (const float*)d_in[2];  // (DH, DIN)
    const float* W_hh   = (const float*)d_in[3];  // (DH, DH)
    const float* b_h    = (const float*)d_in[4];  // (DH,)
    const float* W_ho_w = (const float*)d_in[5];  // (DOUT, DH)
    const float* W_ho_b = (const float*)d_in[6];  // (DOUT,)
    float* out = (float*)d_out;                   // (SEQ*DOUT) then (DH,)

    float* xw = (float*)d_ws;                     // SEQ*DH fp32 = 64 MB
    float* hs = xw + (size_t)SEQ * DH;            // SEQ*DH fp32 = 64 MB

    // 1) sentinel-fill hs (dataflow flags)
    fill_sent_kernel<<<2048, 256, 0, stream>>>((uint4*)hs, (size_t)SEQ * DH / 4);

    // 2) xw = x_seq @ W_ih.T + b_h    (128x64 tiles)
    gemm_nt_bias<<<dim3(SEQ / 128, DH / 64), 256, 0, stream>>>(
        x_seq, W_ih, b_h, xw, SEQ, DH, DIN);

    // 3) sequential recurrence (persistent dataflow kernel, single-barrier)
    rnn_recurrence<<<DH / 16, 512, 0, stream>>>(W_hh, xw, h0, hs);

    // 4) out = hs @ W_ho_w.T + W_ho_b  (128x64 tiles)
    gemm_nt_bias<<<dim3(SEQ / 128, DOUT / 64), 256, 0, stream>>>(
        hs, W_ho_w, W_ho_b, out, SEQ, DOUT, DH);

    // 5) h_final
    copy_hfinal<<<DH / 256, 256, 0, stream>>>(hs, out + (size_t)SEQ * DOUT);
}

// Round 19
// 14375.925 us; speedup vs baseline: 1.5794x; 1.0135x over previous
//
#include <hip/hip_runtime.h>
#include <hip/hip_bf16.h>

// Problem sizes (fixed by the reference)
#define SEQ   8192
#define DIN   1024
#define DH    2048
#define DOUT  1024

#define SENT 0x7fc0deadu  // quiet-NaN payload; tanh output can never equal this

typedef __attribute__((ext_vector_type(8))) short bf16frag;  // 8 bf16 (4 VGPRs)
typedef __attribute__((ext_vector_type(4))) float f32x4;

// ---------------------------------------------------------------------------
// Fill hs with sentinel (must run every launch: harness does not re-poison ws)
// ---------------------------------------------------------------------------
__global__ __launch_bounds__(256) void fill_sent_kernel(uint4* __restrict__ p, size_t n4) {
    size_t i = (size_t)blockIdx.x * blockDim.x + threadIdx.x;
    size_t stride = (size_t)gridDim.x * blockDim.x;
    uint4 v = make_uint4(SENT, SENT, SENT, SENT);
    for (; i < n4; i += stride) p[i] = v;
}

// ---------------------------------------------------------------------------
// fp32 -> bf16 (RNE) converter, float4-in / ushort4-out
// ---------------------------------------------------------------------------
static __device__ inline unsigned short f2bf(float f) {
    unsigned u = __float_as_uint(f);
    u += 0x7fffu + ((u >> 16) & 1u);
    return (unsigned short)(u >> 16);
}
__global__ __launch_bounds__(256) void cvt_bf16_kernel(
    const float4* __restrict__ src, ushort4* __restrict__ dst, size_t n4) {
    size_t i = (size_t)blockIdx.x * blockDim.x + threadIdx.x;
    size_t stride = (size_t)gridDim.x * blockDim.x;
    for (; i < n4; i += stride) {
        const float4 v = src[i];
        ushort4 o;
        o.x = f2bf(v.x); o.y = f2bf(v.y); o.z = f2bf(v.z); o.w = f2bf(v.w);
        dst[i] = o;
    }
}

// ---------------------------------------------------------------------------
// C[m][n] = bias[n] + sum_k A[m][k] * B[n][k]    (A: MxK, B: NxK, C: MxN)
// 128x64 tile, BK=16, 256 threads, 8x4 per-thread accumulators. fp32. (R17)
// Used for xw only -- xw feeds the recurrence and must stay fp32.
// ---------------------------------------------------------------------------
__global__ __launch_bounds__(256) void gemm_nt_bias(
    const float* __restrict__ A, const float* __restrict__ B,
    const float* __restrict__ bias, float* __restrict__ C,
    int M, int N, int K) {
    __shared__ float As[16][132];
    __shared__ float Bs[16][68];
    const int tid = threadIdx.x;
    const int bm = blockIdx.x * 128;
    const int bn = blockIdx.y * 64;
    const int alr = tid >> 1;
    const int alk = (tid & 1) * 8;
    const int blr = tid >> 2;
    const int blk = (tid & 3) * 4;
    const int tm = (tid >> 4) * 8;
    const int tn = (tid & 15) * 4;
    float acc[8][4] = {};

    for (int k0 = 0; k0 < K; k0 += 16) {
        const float4 a0 = *(const float4*)&A[(size_t)(bm + alr) * K + k0 + alk];
        const float4 a1 = *(const float4*)&A[(size_t)(bm + alr) * K + k0 + alk + 4];
        const float4 bv = *(const float4*)&B[(size_t)(bn + blr) * K + k0 + blk];
        As[alk + 0][alr] = a0.x; As[alk + 1][alr] = a0.y;
        As[alk + 2][alr] = a0.z; As[alk + 3][alr] = a0.w;
        As[alk + 4][alr] = a1.x; As[alk + 5][alr] = a1.y;
        As[alk + 6][alr] = a1.z; As[alk + 7][alr] = a1.w;
        Bs[blk + 0][blr] = bv.x; Bs[blk + 1][blr] = bv.y;
        Bs[blk + 2][blr] = bv.z; Bs[blk + 3][blr] = bv.w;
        __syncthreads();
#pragma unroll
        for (int k = 0; k < 16; ++k) {
            const float4 af0 = *(const float4*)&As[k][tm];
            const float4 af1 = *(const float4*)&As[k][tm + 4];
            const float4 bf  = *(const float4*)&Bs[k][tn];
            const float a[8] = {af0.x, af0.y, af0.z, af0.w,
                                af1.x, af1.y, af1.z, af1.w};
            const float b[4] = {bf.x, bf.y, bf.z, bf.w};
#pragma unroll
            for (int i = 0; i < 8; ++i)
#pragma unroll
                for (int j = 0; j < 4; ++j)
                    acc[i][j] = fmaf(a[i], b[j], acc[i][j]);
        }
        __syncthreads();
    }

    const float4 bv = *(const float4*)&bias[bn + tn];
#pragma unroll
    for (int i = 0; i < 8; ++i) {
        float4 o;
        o.x = acc[i][0] + bv.x;
        o.y = acc[i][1] + bv.y;
        o.z = acc[i][2] + bv.z;
        o.w = acc[i][3] + bv.w;
        *(float4*)&C[(size_t)(bm + tm + i) * N + bn + tn] = o;
    }
}

// ---------------------------------------------------------------------------
// bf16 MFMA GEMM for the OUTPUT projection (last op -- rounding does NOT
// amplify through the recurrence). C[m][n] = bias[n] + sum_k A[m][k]*B[n][k],
// A,B bf16 row-major, C fp32. 64x64 tile, 4 waves x (16 rows x 64 cols),
// mfma_f32_16x16x32_bf16. Layouts per verified m89 mapping:
//   A-frag: lane holds A[row=lane&15][k0 + (lane>>4)*8 + j]  (16B load)
//   B-frag: lane holds B[col=lane&15][k0 + (lane>>4)*8 + j]  (16B load)
//   C/D:    reg i -> row (lane>>4)*4+i, col lane&15
// ---------------------------------------------------------------------------
__global__ __launch_bounds__(256) void gemm_bf16_mfma(
    const unsigned short* __restrict__ A, const unsigned short* __restrict__ B,
    const float* __restrict__ bias, float* __restrict__ C,
    int M, int N, int K) {
    const int tid = threadIdx.x;
    const int wave = tid >> 6;
    const int lane = tid & 63;
    const int bm = blockIdx.x * 64 + wave * 16;  // this wave's 16 rows
    const int bn = blockIdx.y * 64;
    const int r  = lane & 15;
    const int ks = (lane >> 4) * 8;

    f32x4 acc[4] = {};
    const unsigned short* arow = A + (size_t)(bm + r) * K + ks;
    const unsigned short* brow = B + (size_t)(bn + r) * K + ks;

    for (int k0 = 0; k0 < K; k0 += 32) {
        const bf16frag a = *(const bf16frag*)(arow + k0);
#pragma unroll
        for (int ct = 0; ct < 4; ++ct) {
            const bf16frag b = *(const bf16frag*)(brow + (size_t)ct * 16 * K + k0);
            acc[ct] = __builtin_amdgcn_mfma_f32_16x16x32_bf16(a, b, acc[ct], 0, 0, 0);
        }
    }

    const int orow = bm + (lane >> 4) * 4;
#pragma unroll
    for (int ct = 0; ct < 4; ++ct) {
        const int col = bn + ct * 16 + (lane & 15);
        const float bv = bias[col];
#pragma unroll
        for (int i = 0; i < 4; ++i)
            C[(size_t)(orow + i) * N + col] = acc[ct][i] + bv;
    }
}

// ---------------------------------------------------------------------------
// Persistent recurrence R18 (FROZEN): 128 WGs x 512 threads, column-
// partitioned, ONE barrier per step. thread tid owns h columns
// [4*tid,4*tid+4) == the 16B it polls; poll -> registers -> immediate
// 16-row x 4-col partial FMAs; 4-stage select-merge (lane ends with row
// lane&15) + xor16/32; per-wave partials to parity-buffered LDS; one
// __syncthreads; tid<16 finalizes + publishes the single 16-lane 64B
// FULL-LINE store (R10/R11: quarter-lines cost 2x WRITE amplification).
// Detect-pipelining class retired (0/3 correct, drain math net-negative).
// ---------------------------------------------------------------------------
__global__ __attribute__((amdgpu_flat_work_group_size(512, 512),
                          amdgpu_waves_per_eu(2, 2)))
void rnn_recurrence(
    const float* __restrict__ Whh, const float* __restrict__ xw,
    const float* __restrict__ h0, float* __restrict__ hs) {
    __shared__ float part[2][8][16];
    const int tid = threadIdx.x;
    const int wave = tid >> 6;
    const int lane = tid & 63;
    const int rbase = blockIdx.x * 16;   // this WG's 16 output rows
    const int c0 = 4 * tid;              // this thread's 4 h-columns

    float4 w[16];
#pragma unroll
    for (int r = 0; r < 16; ++r) {
        w[r] = *(const float4*)&Whh[(size_t)(rbase + r) * DH + c0];
        asm volatile("" : "+v"(w[r].x), "+v"(w[r].y), "+v"(w[r].z), "+v"(w[r].w));
    }

    for (int t = 0; t < SEQ; ++t) {
        const int par = t & 1;
        float xwv = 0.f;
        if (tid < 16) xwv = xw[(size_t)t * DH + rbase + tid];

        float4 hv;
        if (t == 0) {
            hv = *(const float4*)&h0[c0];
        } else {
            const float* a0 = hs + (size_t)(t - 1) * DH + c0;
            unsigned bad;
            do {
                asm volatile(
                    "global_load_dwordx4 %0, %1, off sc0 sc1\n\t"
                    "s_waitcnt vmcnt(0)"
                    : "=&v"(hv) : "v"(a0) : "memory");
                bad = (__float_as_uint(hv.x) == SENT) | (__float_as_uint(hv.y) == SENT) |
                      (__float_as_uint(hv.z) == SENT) | (__float_as_uint(hv.w) == SENT);
            } while (__builtin_expect(bad != 0, 0));
        }

        float acc[16];
#pragma unroll
        for (int r = 0; r < 16; ++r)
            acc[r] = fmaf(w[r].w, hv.w,
                     fmaf(w[r].z, hv.z,
                     fmaf(w[r].y, hv.y, w[r].x * hv.x)));

        const bool b0 = (lane & 1) != 0, b1 = (lane & 2) != 0,
                   b2 = (lane & 4) != 0, b3 = (lane & 8) != 0;
        float s8[8];
#pragma unroll
        for (int j = 0; j < 8; ++j) {
            const float k = b0 ? acc[2 * j + 1] : acc[2 * j];
            const float g = b0 ? acc[2 * j]     : acc[2 * j + 1];
            s8[j] = k + __shfl_xor(g, 1);
        }
        float s4[4];
#pragma unroll
        for (int j = 0; j < 4; ++j) {
            const float k = b1 ? s8[2 * j + 1] : s8[2 * j];
            const float g = b1 ? s8[2 * j]     : s8[2 * j + 1];
            s4[j] = k + __shfl_xor(g, 2);
        }
        float s2[2];
#pragma unroll
        for (int j = 0; j < 2; ++j) {
            const float k = b2 ? s4[2 * j + 1] : s4[2 * j];
            const float g = b2 ? s4[2 * j]     : s4[2 * j + 1];
            s2[j] = k + __shfl_xor(g, 4);
        }
        float s1;
        {
            const float k = b3 ? s2[1] : s2[0];
            const float g = b3 ? s2[0] : s2[1];
            s1 = k + __shfl_xor(g, 8);
        }
        s1 += __shfl_xor(s1, 16);
        s1 += __shfl_xor(s1, 32);

        if (lane < 16) part[par][wave][lane] = s1;
        __syncthreads();

        if (tid < 16) {
            const float sum =
                part[par][0][tid] + part[par][1][tid] + part[par][2][tid] +
                part[par][3][tid] + part[par][4][tid] + part[par][5][tid] +
                part[par][6][tid] + part[par][7][tid];
            const float hval = tanhf(sum + xwv);
            __hip_atomic_store((unsigned*)(hs + (size_t)t * DH + rbase + tid),
                               __float_as_uint(hval),
                               __ATOMIC_RELAXED, __HIP_MEMORY_SCOPE_AGENT);
        }
    }
}

// ---------------------------------------------------------------------------
__global__ __launch_bounds__(256) void copy_hfinal(const float* __restrict__ hs,
                                                   float* __restrict__ out) {
    const int i = blockIdx.x * 256 + threadIdx.x;
    out[i] = hs[(size_t)(SEQ - 1) * DH + i];
}

// ---------------------------------------------------------------------------
extern "C" void kernel_launch(void* const* d_in, const int* in_sizes, int n_in,
                              void* d_out, int out_size, void* d_ws, size_t ws_size,
                              hipStream_t stream) {
    (void)in_sizes; (void)n_in; (void)out_size; (void)ws_size;
    const float* x_seq  = (const float*)d_in[0];  // (SEQ, DIN)
    const float* h0     = (const float*)d_in[1];  // (DH,)
    const float* W_ih   = (const float*)d_in[2];  // (DH, DIN)
    const float* W_hh   = (const float*)d_in[3];  // (DH, DH)
    const float* b_h    = (const float*)d_in[4];  // (DH,)
    const float* W_ho_w = (const float*)d_in[5];  // (DOUT, DH)
    const float* W_ho_b = (const float*)d_in[6];  // (DOUT,)
    float* out = (float*)d_out;                   // (SEQ*DOUT) then (DH,)

    float* xw = (float*)d_ws;                     // SEQ*DH fp32 = 64 MB
    float* hs = xw + (size_t)SEQ * DH;            // SEQ*DH fp32 = 64 MB
    // After the recurrence, xw is dead -- reuse it for the bf16 copies
    // (stream order guarantees the recurrence finished first).
    unsigned short* hsb = (unsigned short*)xw;                  // 32 MB
    unsigned short* wob = hsb + (size_t)SEQ * DH;               // 2 MB

    // 1) sentinel-fill hs (dataflow flags)
    fill_sent_kernel<<<2048, 256, 0, stream>>>((uint4*)hs, (size_t)SEQ * DH / 4);

    // 2) xw = x_seq @ W_ih.T + b_h    (fp32 -- feeds the recurrence)
    gemm_nt_bias<<<dim3(SEQ / 128, DH / 64), 256, 0, stream>>>(
        x_seq, W_ih, b_h, xw, SEQ, DH, DIN);

    // 3) sequential recurrence (persistent dataflow kernel, R18 frozen)
    rnn_recurrence<<<DH / 16, 512, 0, stream>>>(W_hh, xw, h0, hs);

    // 4) convert hs and W_ho_w to bf16 (into the dead xw buffer)
    cvt_bf16_kernel<<<2048, 256, 0, stream>>>(
        (const float4*)hs, (ushort4*)hsb, (size_t)SEQ * DH / 4);
    cvt_bf16_kernel<<<1024, 256, 0, stream>>>(
        (const float4*)W_ho_w, (ushort4*)wob, (size_t)DOUT * DH / 4);

    // 5) out = hs @ W_ho_w.T + W_ho_b  (bf16 MFMA, fp32 accumulate)
    gemm_bf16_mfma<<<dim3(SEQ / 64, DOUT / 64), 256, 0, stream>>>(
        hsb, wob, W_ho_b, out, SEQ, DOUT, DH);

    // 6) h_final
    copy_hfinal<<<DH / 256, 256, 0, stream>>>(hs, out + (size_t)SEQ * DOUT);
}

// Round 20
// 14345.799 us; speedup vs baseline: 1.5827x; 1.0021x over previous
//
#include <hip/hip_runtime.h>
#include <hip/hip_bf16.h>

// Problem sizes (fixed by the reference)
#define SEQ   8192
#define DIN   1024
#define DH    2048
#define DOUT  1024

#define SENT 0x7fc0deadu  // quiet-NaN payload; real data can never equal this

typedef __attribute__((ext_vector_type(8))) short bf16frag;  // 8 bf16 (4 VGPRs)
typedef __attribute__((ext_vector_type(4))) float f32x4;

// ---------------------------------------------------------------------------
// Fill region with sentinel (must run every launch; ws is not re-poisoned)
// ---------------------------------------------------------------------------
__global__ __launch_bounds__(256) void fill_sent_kernel(uint4* __restrict__ p, size_t n4) {
    size_t i = (size_t)blockIdx.x * blockDim.x + threadIdx.x;
    size_t stride = (size_t)gridDim.x * blockDim.x;
    uint4 v = make_uint4(SENT, SENT, SENT, SENT);
    for (; i < n4; i += stride) p[i] = v;
}

// ---------------------------------------------------------------------------
// fp32 -> bf16 (RNE) converter, float4-in / ushort4-out
// ---------------------------------------------------------------------------
static __device__ inline unsigned short f2bf(float f) {
    unsigned u = __float_as_uint(f);
    u += 0x7fffu + ((u >> 16) & 1u);
    return (unsigned short)(u >> 16);
}
__global__ __launch_bounds__(256) void cvt_bf16_kernel(
    const float4* __restrict__ src, ushort4* __restrict__ dst, size_t n4) {
    size_t i = (size_t)blockIdx.x * blockDim.x + threadIdx.x;
    size_t stride = (size_t)gridDim.x * blockDim.x;
    for (; i < n4; i += stride) {
        const float4 v = src[i];
        ushort4 o;
        o.x = f2bf(v.x); o.y = f2bf(v.y); o.z = f2bf(v.z); o.w = f2bf(v.w);
        dst[i] = o;
    }
}

// ---------------------------------------------------------------------------
// bf16 MFMA GEMM for the OUTPUT projection (last op -- rounding does NOT
// amplify). C = bias + A@B^T, A,B bf16 row-major, C fp32. 64x64 tile,
// 4 waves x (16 rows x 64 cols), mfma_f32_16x16x32_bf16 (verified m89 maps).
// ---------------------------------------------------------------------------
__global__ __launch_bounds__(256) void gemm_bf16_mfma(
    const unsigned short* __restrict__ A, const unsigned short* __restrict__ B,
    const float* __restrict__ bias, float* __restrict__ C,
    int M, int N, int K) {
    const int tid = threadIdx.x;
    const int wave = tid >> 6;
    const int lane = tid & 63;
    const int bm = blockIdx.x * 64 + wave * 16;
    const int bn = blockIdx.y * 64;
    const int r  = lane & 15;
    const int ks = (lane >> 4) * 8;

    f32x4 acc[4] = {};
    const unsigned short* arow = A + (size_t)(bm + r) * K + ks;
    const unsigned short* brow = B + (size_t)(bn + r) * K + ks;

    for (int k0 = 0; k0 < K; k0 += 32) {
        const bf16frag a = *(const bf16frag*)(arow + k0);
#pragma unroll
        for (int ct = 0; ct < 4; ++ct) {
            const bf16frag b = *(const bf16frag*)(brow + (size_t)ct * 16 * K + k0);
            acc[ct] = __builtin_amdgcn_mfma_f32_16x16x32_bf16(a, b, acc[ct], 0, 0, 0);
        }
    }

    const int orow = bm + (lane >> 4) * 4;
#pragma unroll
    for (int ct = 0; ct < 4; ++ct) {
        const int col = bn + ct * 16 + (lane & 15);
        const float bv = bias[col];
#pragma unroll
        for (int i = 0; i < 4; ++i)
            C[(size_t)(orow + i) * N + col] = acc[ct][i] + bv;
    }
}

// ---------------------------------------------------------------------------
// FUSED kernel: blocks 0..127 = R18 recurrence (frozen); blocks 128..2175 =
// xw-GEMM worker tiles (R17 body, masked tid<256, bit-identical fp32 math).
// xw is sentinel-filled; workers publish via word-atomic agent stores (the
// R10-proven producer path); recurrence consumers poll their single xw word
// with sc0sc1 loads, issued EARLY (drained for free inside the h-poll's
// vmcnt(0)) and checked after the barrier -> zero added critical path when
// the GEMM runs ahead (it produces ~10x faster than consumption).
// Deadlock-free by capacity: workers never poll (always retire); 128
// recurrence WGs < 256 CUs, so workers always have CUs. Worst-case dispatch
// order degenerates to serial (= R19 behavior).
// ---------------------------------------------------------------------------
__global__ __attribute__((amdgpu_flat_work_group_size(512, 512),
                          amdgpu_waves_per_eu(2, 2)))
void fused_rnn(
    const float* __restrict__ Whh, float* __restrict__ xw,
    const float* __restrict__ x_seq, const float* __restrict__ W_ih,
    const float* __restrict__ b_h,
    const float* __restrict__ h0, float* __restrict__ hs) {
    __shared__ float part[2][8][16];
    __shared__ float As[16][132];
    __shared__ float Bs[16][68];
    const int tid = threadIdx.x;

    if (blockIdx.x >= 128) {
        // ------------------- xw-GEMM worker (R17 body, tid<256) -----------
        const int tau = blockIdx.x - 128;          // 0..2047, bm-major
        const int bm = (tau >> 5) * 128;           // SEQ/128 = 64 row blocks
        const int bn = (tau & 31) * 64;            // DH/64  = 32 col blocks
        const int K = DIN, N = DH;
        const int alr = tid >> 1;
        const int alk = (tid & 1) * 8;
        const int blr = tid >> 2;
        const int blk = (tid & 3) * 4;
        const int tm = (tid >> 4) * 8;
        const int tn = (tid & 15) * 4;
        float acc[8][4] = {};

        for (int k0 = 0; k0 < K; k0 += 16) {
            if (tid < 256) {
                const float4 a0 = *(const float4*)&x_seq[(size_t)(bm + alr) * K + k0 + alk];
                const float4 a1 = *(const float4*)&x_seq[(size_t)(bm + alr) * K + k0 + alk + 4];
                const float4 bv = *(const float4*)&W_ih[(size_t)(bn + blr) * K + k0 + blk];
                As[alk + 0][alr] = a0.x; As[alk + 1][alr] = a0.y;
                As[alk + 2][alr] = a0.z; As[alk + 3][alr] = a0.w;
                As[alk + 4][alr] = a1.x; As[alk + 5][alr] = a1.y;
                As[alk + 6][alr] = a1.z; As[alk + 7][alr] = a1.w;
                Bs[blk + 0][blr] = bv.x; Bs[blk + 1][blr] = bv.y;
                Bs[blk + 2][blr] = bv.z; Bs[blk + 3][blr] = bv.w;
            }
            __syncthreads();
            if (tid < 256) {
#pragma unroll
                for (int k = 0; k < 16; ++k) {
                    const float4 af0 = *(const float4*)&As[k][tm];
                    const float4 af1 = *(const float4*)&As[k][tm + 4];
                    const float4 bf  = *(const float4*)&Bs[k][tn];
                    const float a[8] = {af0.x, af0.y, af0.z, af0.w,
                                        af1.x, af1.y, af1.z, af1.w};
                    const float b[4] = {bf.x, bf.y, bf.z, bf.w};
#pragma unroll
                    for (int i = 0; i < 8; ++i)
#pragma unroll
                        for (int j = 0; j < 4; ++j)
                            acc[i][j] = fmaf(a[i], b[j], acc[i][j]);
                }
            }
            __syncthreads();
        }

        if (tid < 256) {
            const float4 bv = *(const float4*)&b_h[bn + tn];
#pragma unroll
            for (int i = 0; i < 8; ++i) {
                const float o0 = acc[i][0] + bv.x;
                const float o1 = acc[i][1] + bv.y;
                const float o2 = acc[i][2] + bv.z;
                const float o3 = acc[i][3] + bv.w;
                unsigned* dst = (unsigned*)&xw[(size_t)(bm + tm + i) * N + bn + tn];
                __hip_atomic_store(dst + 0, __float_as_uint(o0),
                                   __ATOMIC_RELAXED, __HIP_MEMORY_SCOPE_AGENT);
                __hip_atomic_store(dst + 1, __float_as_uint(o1),
                                   __ATOMIC_RELAXED, __HIP_MEMORY_SCOPE_AGENT);
                __hip_atomic_store(dst + 2, __float_as_uint(o2),
                                   __ATOMIC_RELAXED, __HIP_MEMORY_SCOPE_AGENT);
                __hip_atomic_store(dst + 3, __float_as_uint(o3),
                                   __ATOMIC_RELAXED, __HIP_MEMORY_SCOPE_AGENT);
            }
        }
        return;
    }

    // ------------------- recurrence (R18 frozen + xw word-poll) -----------
    const int wave = tid >> 6;
    const int lane = tid & 63;
    const int rbase = blockIdx.x * 16;   // this WG's 16 output rows
    const int c0 = 4 * tid;              // this thread's 4 h-columns

    float4 w[16];
#pragma unroll
    for (int r = 0; r < 16; ++r) {
        w[r] = *(const float4*)&Whh[(size_t)(rbase + r) * DH + c0];
        asm volatile("" : "+v"(w[r].x), "+v"(w[r].y), "+v"(w[r].z), "+v"(w[r].w));
    }

    for (int t = 0; t < SEQ; ++t) {
        const int par = t & 1;

        // early-issue this step's xw word (in-flight; drained by the h-poll's
        // vmcnt(0) or the explicit one below -- never dangles across a
        // back-edge, so no R14-16-class hazard)
        float xwv = 0.f;
        const float* xaddr = xw + (size_t)t * DH + rbase + tid;
        if (tid < 16)
            asm volatile("global_load_dword %0, %1, off sc0 sc1"
                         : "=&v"(xwv) : "v"(xaddr) : "memory");

        float4 hv;
        if (t == 0) {
            hv = *(const float4*)&h0[c0];
        } else {
            const float* a0 = hs + (size_t)(t - 1) * DH + c0;
            unsigned bad;
            do {
                asm volatile(
                    "global_load_dwordx4 %0, %1, off sc0 sc1\n\t"
                    "s_waitcnt vmcnt(0)"
                    : "=&v"(hv) : "v"(a0) : "memory");
                bad = (__float_as_uint(hv.x) == SENT) | (__float_as_uint(hv.y) == SENT) |
                      (__float_as_uint(hv.z) == SENT) | (__float_as_uint(hv.w) == SENT);
            } while (__builtin_expect(bad != 0, 0));
        }

        float acc[16];
#pragma unroll
        for (int r = 0; r < 16; ++r)
            acc[r] = fmaf(w[r].w, hv.w,
                     fmaf(w[r].z, hv.z,
                     fmaf(w[r].y, hv.y, w[r].x * hv.x)));

        const bool b0 = (lane & 1) != 0, b1 = (lane & 2) != 0,
                   b2 = (lane & 4) != 0, b3 = (lane & 8) != 0;
        float s8[8];
#pragma unroll
        for (int j = 0; j < 8; ++j) {
            const float k = b0 ? acc[2 * j + 1] : acc[2 * j];
            const float g = b0 ? acc[2 * j]     : acc[2 * j + 1];
            s8[j] = k + __shfl_xor(g, 1);
        }
        float s4[4];
#pragma unroll
        for (int j = 0; j < 4; ++j) {
            const float k = b1 ? s8[2 * j + 1] : s8[2 * j];
            const float g = b1 ? s8[2 * j]     : s8[2 * j + 1];
            s4[j] = k + __shfl_xor(g, 2);
        }
        float s2[2];
#pragma unroll
        for (int j = 0; j < 2; ++j) {
            const float k = b2 ? s4[2 * j + 1] : s4[2 * j];
            const float g = b2 ? s4[2 * j]     : s4[2 * j + 1];
            s2[j] = k + __shfl_xor(g, 4);
        }
        float s1;
        {
            const float k = b3 ? s2[1] : s2[0];
            const float g = b3 ? s2[0] : s2[1];
            s1 = k + __shfl_xor(g, 8);
        }
        s1 += __shfl_xor(s1, 16);
        s1 += __shfl_xor(s1, 32);

        if (lane < 16) part[par][wave][lane] = s1;
        __syncthreads();

        if (tid < 16) {
            // xw word: common case already arrived (GEMM runs far ahead)
            asm volatile("s_waitcnt vmcnt(0)" ::: "memory");
            __builtin_amdgcn_sched_barrier(0);
            while (__builtin_expect(__float_as_uint(xwv) == SENT, 0)) {
                asm volatile(
                    "global_load_dword %0, %1, off sc0 sc1\n\t"
                    "s_waitcnt vmcnt(0)"
                    : "=&v"(xwv) : "v"(xaddr) : "memory");
            }
            const float sum =
                part[par][0][tid] + part[par][1][tid] + part[par][2][tid] +
                part[par][3][tid] + part[par][4][tid] + part[par][5][tid] +
                part[par][6][tid] + part[par][7][tid];
            const float hval = tanhf(sum + xwv);
            __hip_atomic_store((unsigned*)(hs + (size_t)t * DH + rbase + tid),
                               __float_as_uint(hval),
                               __ATOMIC_RELAXED, __HIP_MEMORY_SCOPE_AGENT);
        }
    }
}

// ---------------------------------------------------------------------------
__global__ __launch_bounds__(256) void copy_hfinal(const float* __restrict__ hs,
                                                   float* __restrict__ out) {
    const int i = blockIdx.x * 256 + threadIdx.x;
    out[i] = hs[(size_t)(SEQ - 1) * DH + i];
}

// ---------------------------------------------------------------------------
extern "C" void kernel_launch(void* const* d_in, const int* in_sizes, int n_in,
                              void* d_out, int out_size, void* d_ws, size_t ws_size,
                              hipStream_t stream) {
    (void)in_sizes; (void)n_in; (void)out_size; (void)ws_size;
    const float* x_seq  = (const float*)d_in[0];  // (SEQ, DIN)
    const float* h0     = (const float*)d_in[1];  // (DH,)
    const float* W_ih   = (const float*)d_in[2];  // (DH, DIN)
    const float* W_hh   = (const float*)d_in[3];  // (DH, DH)
    const float* b_h    = (const float*)d_in[4];  // (DH,)
    const float* W_ho_w = (const float*)d_in[5];  // (DOUT, DH)
    const float* W_ho_b = (const float*)d_in[6];  // (DOUT,)
    float* out = (float*)d_out;                   // (SEQ*DOUT) then (DH,)

    float* xw = (float*)d_ws;                     // SEQ*DH fp32 = 64 MB
    float* hs = xw + (size_t)SEQ * DH;            // SEQ*DH fp32 = 64 MB
    // After the fused kernel, xw is dead -- reuse for bf16 copies.
    unsigned short* hsb = (unsigned short*)xw;                  // 32 MB
    unsigned short* wob = hsb + (size_t)SEQ * DH;               // 2 MB

    // 1) sentinel-fill BOTH xw and hs (contiguous 128 MB)
    fill_sent_kernel<<<4096, 256, 0, stream>>>((uint4*)xw,
                                               (size_t)2 * SEQ * DH / 4);

    // 2) FUSED: recurrence (blocks 0..127) + xw-GEMM producers (128..2175)
    fused_rnn<<<128 + 2048, 512, 0, stream>>>(W_hh, xw, x_seq, W_ih, b_h,
                                              h0, hs);

    // 3) convert hs and W_ho_w to bf16 (into the dead xw buffer)
    cvt_bf16_kernel<<<2048, 256, 0, stream>>>(
        (const float4*)hs, (ushort4*)hsb, (size_t)SEQ * DH / 4);
    cvt_bf16_kernel<<<1024, 256, 0, stream>>>(
        (const float4*)W_ho_w, (ushort4*)wob, (size_t)DOUT * DH / 4);

    // 4) out = hs @ W_ho_w.T + W_ho_b  (bf16 MFMA, fp32 accumulate)
    gemm_bf16_mfma<<<dim3(SEQ / 64, DOUT / 64), 256, 0, stream>>>(
        hsb, wob, W_ho_b, out, SEQ, DOUT, DH);

    // 5) h_final
    copy_hfinal<<<DH / 256, 256, 0, stream>>>(hs, out + (size_t)SEQ * DOUT);
}

// Round 21
// 14202.054 us; speedup vs baseline: 1.5987x; 1.0101x over previous
//
#include <hip/hip_runtime.h>
#include <hip/hip_bf16.h>

// Problem sizes (fixed by the reference)
#define SEQ   8192
#define DIN   1024
#define DH    2048
#define DOUT  1024

#define SENT 0x7fc0deadu  // quiet-NaN payload; real data can never equal this

typedef __attribute__((ext_vector_type(8))) short bf16frag;  // 8 bf16 (4 VGPRs)
typedef __attribute__((ext_vector_type(4))) float f32x4;

// ---------------------------------------------------------------------------
// Fill region with sentinel (must run every launch; ws is not re-poisoned)
// ---------------------------------------------------------------------------
__global__ __launch_bounds__(256) void fill_sent_kernel(uint4* __restrict__ p, size_t n4) {
    size_t i = (size_t)blockIdx.x * blockDim.x + threadIdx.x;
    size_t stride = (size_t)gridDim.x * blockDim.x;
    uint4 v = make_uint4(SENT, SENT, SENT, SENT);
    for (; i < n4; i += stride) p[i] = v;
}

// ---------------------------------------------------------------------------
// fp32 -> bf16 (RNE)
// ---------------------------------------------------------------------------
static __device__ inline unsigned short f2bf(float f) {
    unsigned u = __float_as_uint(f);
    u += 0x7fffu + ((u >> 16) & 1u);
    return (unsigned short)(u >> 16);
}
__global__ __launch_bounds__(256) void cvt_bf16_kernel(
    const float4* __restrict__ src, ushort4* __restrict__ dst, size_t n4) {
    size_t i = (size_t)blockIdx.x * blockDim.x + threadIdx.x;
    size_t stride = (size_t)gridDim.x * blockDim.x;
    for (; i < n4; i += stride) {
        const float4 v = src[i];
        ushort4 o;
        o.x = f2bf(v.x); o.y = f2bf(v.y); o.z = f2bf(v.z); o.w = f2bf(v.w);
        dst[i] = o;
    }
}

// ---------------------------------------------------------------------------
// bf16 MFMA GEMM for the OUTPUT projection (last op -- rounding does NOT
// amplify). C = bias + A@B^T, A,B bf16 row-major, C fp32. 64x64 tile,
// 4 waves x (16 rows x 64 cols), mfma_f32_16x16x32_bf16 (verified m89 maps).
// ---------------------------------------------------------------------------
__global__ __launch_bounds__(256) void gemm_bf16_mfma(
    const unsigned short* __restrict__ A, const unsigned short* __restrict__ B,
    const float* __restrict__ bias, float* __restrict__ C,
    int M, int N, int K) {
    const int tid = threadIdx.x;
    const int wave = tid >> 6;
    const int lane = tid & 63;
    const int bm = blockIdx.x * 64 + wave * 16;
    const int bn = blockIdx.y * 64;
    const int r  = lane & 15;
    const int ks = (lane >> 4) * 8;

    f32x4 acc[4] = {};
    const unsigned short* arow = A + (size_t)(bm + r) * K + ks;
    const unsigned short* brow = B + (size_t)(bn + r) * K + ks;

    for (int k0 = 0; k0 < K; k0 += 32) {
        const bf16frag a = *(const bf16frag*)(arow + k0);
#pragma unroll
        for (int ct = 0; ct < 4; ++ct) {
            const bf16frag b = *(const bf16frag*)(brow + (size_t)ct * 16 * K + k0);
            acc[ct] = __builtin_amdgcn_mfma_f32_16x16x32_bf16(a, b, acc[ct], 0, 0, 0);
        }
    }

    const int orow = bm + (lane >> 4) * 4;
#pragma unroll
    for (int ct = 0; ct < 4; ++ct) {
        const int col = bn + ct * 16 + (lane & 15);
        const float bv = bias[col];
#pragma unroll
        for (int i = 0; i < 4; ++i)
            C[(size_t)(orow + i) * N + col] = acc[ct][i] + bv;
    }
}

// ---------------------------------------------------------------------------
// FUSED kernel (R20 structure): blocks 0..127 = recurrence; 128..2175 =
// xw-GEMM workers. R21 change: recurrence publishers (tid<16) ALSO write the
// bf16 copy of their 16 h-values to hsb inline (one 32B store; completes in
// parallel with the hs publish stores inside the next poll's vmcnt(0);
// nobody polls hsb so its half-line dribble is harmless) -> the 2048-block
// cvt_hs pass is eliminated.
// ---------------------------------------------------------------------------
__global__ __attribute__((amdgpu_flat_work_group_size(512, 512),
                          amdgpu_waves_per_eu(2, 2)))
void fused_rnn(
    const float* __restrict__ Whh, float* __restrict__ xw,
    const float* __restrict__ x_seq, const float* __restrict__ W_ih,
    const float* __restrict__ b_h,
    const float* __restrict__ h0, float* __restrict__ hs,
    unsigned short* __restrict__ hsb) {
    __shared__ float part[2][8][16];
    __shared__ float As[16][132];
    __shared__ float Bs[16][68];
    const int tid = threadIdx.x;

    if (blockIdx.x >= 128) {
        // ------------------- xw-GEMM worker (R17 body, tid<256) -----------
        const int tau = blockIdx.x - 128;          // 0..2047, bm-major
        const int bm = (tau >> 5) * 128;           // SEQ/128 = 64 row blocks
        const int bn = (tau & 31) * 64;            // DH/64  = 32 col blocks
        const int K = DIN, N = DH;
        const int alr = tid >> 1;
        const int alk = (tid & 1) * 8;
        const int blr = tid >> 2;
        const int blk = (tid & 3) * 4;
        const int tm = (tid >> 4) * 8;
        const int tn = (tid & 15) * 4;
        float acc[8][4] = {};

        for (int k0 = 0; k0 < K; k0 += 16) {
            if (tid < 256) {
                const float4 a0 = *(const float4*)&x_seq[(size_t)(bm + alr) * K + k0 + alk];
                const float4 a1 = *(const float4*)&x_seq[(size_t)(bm + alr) * K + k0 + alk + 4];
                const float4 bv = *(const float4*)&W_ih[(size_t)(bn + blr) * K + k0 + blk];
                As[alk + 0][alr] = a0.x; As[alk + 1][alr] = a0.y;
                As[alk + 2][alr] = a0.z; As[alk + 3][alr] = a0.w;
                As[alk + 4][alr] = a1.x; As[alk + 5][alr] = a1.y;
                As[alk + 6][alr] = a1.z; As[alk + 7][alr] = a1.w;
                Bs[blk + 0][blr] = bv.x; Bs[blk + 1][blr] = bv.y;
                Bs[blk + 2][blr] = bv.z; Bs[blk + 3][blr] = bv.w;
            }
            __syncthreads();
            if (tid < 256) {
#pragma unroll
                for (int k = 0; k < 16; ++k) {
                    const float4 af0 = *(const float4*)&As[k][tm];
                    const float4 af1 = *(const float4*)&As[k][tm + 4];
                    const float4 bf  = *(const float4*)&Bs[k][tn];
                    const float a[8] = {af0.x, af0.y, af0.z, af0.w,
                                        af1.x, af1.y, af1.z, af1.w};
                    const float b[4] = {bf.x, bf.y, bf.z, bf.w};
#pragma unroll
                    for (int i = 0; i < 8; ++i)
#pragma unroll
                        for (int j = 0; j < 4; ++j)
                            acc[i][j] = fmaf(a[i], b[j], acc[i][j]);
                }
            }
            __syncthreads();
        }

        if (tid < 256) {
            const float4 bv = *(const float4*)&b_h[bn + tn];
#pragma unroll
            for (int i = 0; i < 8; ++i) {
                const float o0 = acc[i][0] + bv.x;
                const float o1 = acc[i][1] + bv.y;
                const float o2 = acc[i][2] + bv.z;
                const float o3 = acc[i][3] + bv.w;
                unsigned* dst = (unsigned*)&xw[(size_t)(bm + tm + i) * N + bn + tn];
                __hip_atomic_store(dst + 0, __float_as_uint(o0),
                                   __ATOMIC_RELAXED, __HIP_MEMORY_SCOPE_AGENT);
                __hip_atomic_store(dst + 1, __float_as_uint(o1),
                                   __ATOMIC_RELAXED, __HIP_MEMORY_SCOPE_AGENT);
                __hip_atomic_store(dst + 2, __float_as_uint(o2),
                                   __ATOMIC_RELAXED, __HIP_MEMORY_SCOPE_AGENT);
                __hip_atomic_store(dst + 3, __float_as_uint(o3),
                                   __ATOMIC_RELAXED, __HIP_MEMORY_SCOPE_AGENT);
            }
        }
        return;
    }

    // ------------------- recurrence (R18 frozen + xw word-poll) -----------
    const int wave = tid >> 6;
    const int lane = tid & 63;
    const int rbase = blockIdx.x * 16;   // this WG's 16 output rows
    const int c0 = 4 * tid;              // this thread's 4 h-columns

    float4 w[16];
#pragma unroll
    for (int r = 0; r < 16; ++r) {
        w[r] = *(const float4*)&Whh[(size_t)(rbase + r) * DH + c0];
        asm volatile("" : "+v"(w[r].x), "+v"(w[r].y), "+v"(w[r].z), "+v"(w[r].w));
    }

    for (int t = 0; t < SEQ; ++t) {
        const int par = t & 1;

        // early-issue this step's xw word (drained by the h-poll's vmcnt(0))
        float xwv = 0.f;
        const float* xaddr = xw + (size_t)t * DH + rbase + tid;
        if (tid < 16)
            asm volatile("global_load_dword %0, %1, off sc0 sc1"
                         : "=&v"(xwv) : "v"(xaddr) : "memory");

        float4 hv;
        if (t == 0) {
            hv = *(const float4*)&h0[c0];
        } else {
            const float* a0 = hs + (size_t)(t - 1) * DH + c0;
            unsigned bad;
            do {
                asm volatile(
                    "global_load_dwordx4 %0, %1, off sc0 sc1\n\t"
                    "s_waitcnt vmcnt(0)"
                    : "=&v"(hv) : "v"(a0) : "memory");
                bad = (__float_as_uint(hv.x) == SENT) | (__float_as_uint(hv.y) == SENT) |
                      (__float_as_uint(hv.z) == SENT) | (__float_as_uint(hv.w) == SENT);
            } while (__builtin_expect(bad != 0, 0));
        }

        float acc[16];
#pragma unroll
        for (int r = 0; r < 16; ++r)
            acc[r] = fmaf(w[r].w, hv.w,
                     fmaf(w[r].z, hv.z,
                     fmaf(w[r].y, hv.y, w[r].x * hv.x)));

        const bool b0 = (lane & 1) != 0, b1 = (lane & 2) != 0,
                   b2 = (lane & 4) != 0, b3 = (lane & 8) != 0;
        float s8[8];
#pragma unroll
        for (int j = 0; j < 8; ++j) {
            const float k = b0 ? acc[2 * j + 1] : acc[2 * j];
            const float g = b0 ? acc[2 * j]     : acc[2 * j + 1];
            s8[j] = k + __shfl_xor(g, 1);
        }
        float s4[4];
#pragma unroll
        for (int j = 0; j < 4; ++j) {
            const float k = b1 ? s8[2 * j + 1] : s8[2 * j];
            const float g = b1 ? s8[2 * j]     : s8[2 * j + 1];
            s4[j] = k + __shfl_xor(g, 2);
        }
        float s2[2];
#pragma unroll
        for (int j = 0; j < 2; ++j) {
            const float k = b2 ? s4[2 * j + 1] : s4[2 * j];
            const float g = b2 ? s4[2 * j]     : s4[2 * j + 1];
            s2[j] = k + __shfl_xor(g, 4);
        }
        float s1;
        {
            const float k = b3 ? s2[1] : s2[0];
            const float g = b3 ? s2[0] : s2[1];
            s1 = k + __shfl_xor(g, 8);
        }
        s1 += __shfl_xor(s1, 16);
        s1 += __shfl_xor(s1, 32);

        if (lane < 16) part[par][wave][lane] = s1;
        __syncthreads();

        if (tid < 16) {
            // xw word: common case already arrived (GEMM runs far ahead)
            asm volatile("s_waitcnt vmcnt(0)" ::: "memory");
            __builtin_amdgcn_sched_barrier(0);
            while (__builtin_expect(__float_as_uint(xwv) == SENT, 0)) {
                asm volatile(
                    "global_load_dword %0, %1, off sc0 sc1\n\t"
                    "s_waitcnt vmcnt(0)"
                    : "=&v"(xwv) : "v"(xaddr) : "memory");
            }
            const float sum =
                part[par][0][tid] + part[par][1][tid] + part[par][2][tid] +
                part[par][3][tid] + part[par][4][tid] + part[par][5][tid] +
                part[par][6][tid] + part[par][7][tid];
            const float hval = tanhf(sum + xwv);
            __hip_atomic_store((unsigned*)(hs + (size_t)t * DH + rbase + tid),
                               __float_as_uint(hval),
                               __ATOMIC_RELAXED, __HIP_MEMORY_SCOPE_AGENT);
            // inline bf16 copy for the output GEMM (fire-and-forget; nobody
            // polls hsb, completes alongside the hs publish stores)
            hsb[(size_t)t * DH + rbase + tid] = f2bf(hval);
        }
    }
}

// ---------------------------------------------------------------------------
__global__ __launch_bounds__(256) void copy_hfinal(const float* __restrict__ hs,
                                                   float* __restrict__ out) {
    const int i = blockIdx.x * 256 + threadIdx.x;
    out[i] = hs[(size_t)(SEQ - 1) * DH + i];
}

// ---------------------------------------------------------------------------
extern "C" void kernel_launch(void* const* d_in, const int* in_sizes, int n_in,
                              void* d_out, int out_size, void* d_ws, size_t ws_size,
                              hipStream_t stream) {
    (void)in_sizes; (void)n_in; (void)out_size; (void)ws_size;
    const float* x_seq  = (const float*)d_in[0];  // (SEQ, DIN)
    const float* h0     = (const float*)d_in[1];  // (DH,)
    const float* W_ih   = (const float*)d_in[2];  // (DH, DIN)
    const float* W_hh   = (const float*)d_in[3];  // (DH, DH)
    const float* b_h    = (const float*)d_in[4];  // (DH,)
    const float* W_ho_w = (const float*)d_in[5];  // (DOUT, DH)
    const float* W_ho_b = (const float*)d_in[6];  // (DOUT,)
    float* out = (float*)d_out;                   // (SEQ*DOUT) then (DH,)

    float* xw = (float*)d_ws;                     // SEQ*DH fp32 = 64 MB
    float* hs = xw + (size_t)SEQ * DH;            // SEQ*DH fp32 = 64 MB
    unsigned short* hsb = (unsigned short*)(hs + (size_t)SEQ * DH);  // 32 MB
    unsigned short* wob = hsb + (size_t)SEQ * DH;                    // 2 MB

    // 1) sentinel-fill xw and hs (contiguous 128 MB; hsb needs no fill --
    //    out-GEMM runs after fused_rnn completes, plain reads)
    fill_sent_kernel<<<4096, 256, 0, stream>>>((uint4*)xw,
                                               (size_t)2 * SEQ * DH / 4);

    // 2) convert W_ho_w to bf16 (small; runs concurrent with fill)
    cvt_bf16_kernel<<<1024, 256, 0, stream>>>(
        (const float4*)W_ho_w, (ushort4*)wob, (size_t)DOUT * DH / 4);

    // 3) FUSED: recurrence (blocks 0..127, inline bf16-hs) + xw-GEMM workers
    fused_rnn<<<128 + 2048, 512, 0, stream>>>(W_hh, xw, x_seq, W_ih, b_h,
                                              h0, hs, hsb);

    // 4) out = hs @ W_ho_w.T + W_ho_b  (bf16 MFMA, fp32 accumulate)
    gemm_bf16_mfma<<<dim3(SEQ / 64, DOUT / 64), 256, 0, stream>>>(
        hsb, wob, W_ho_b, out, SEQ, DOUT, DH);

    // 5) h_final
    copy_hfinal<<<DH / 256, 256, 0, stream>>>(hs, out + (size_t)SEQ * DOUT);
}